// Round 2
// baseline (919.344 us; speedup 1.0000x reference)
//
#include <hip/hip_runtime.h>
#include <stdint.h>

// H2GCN forward on MI355X (gfx950). Round 8 (= round 7 retry, infra failure):
//  - k_embed restructured: each wave owns 16 rows x full K=512 (no K-split,
//    no LDS reduce, no barrier in the GEMM). acc = 16 VGPR (was 64) -> compiler
//    has headroom to pipeline loads; 256-thread blocks -> 6252 waves.
//  - launch_bounds relaxed (256,4): cap 128 VGPR, no spill risk (was (256,6)).
//  - BN stats: per-block LDS reduce (2 KB) then 128 atomics/block.
//  - Everything else unchanged from round 6.

typedef __bf16 bf16x8 __attribute__((ext_vector_type(8)));
typedef float  f32x4  __attribute__((ext_vector_type(4)));

#define NN   100000
#define EE   800000
#define IND  512
#define HID  64
#define ZD   320
#define CLS  40
#define NCH  98           // ceil(NN/1024)
#define NBLK 1563         // ceil(NN/64) embed blocks

static __device__ __forceinline__ float bf2f(unsigned short s) {
  unsigned int u = ((unsigned int)s) << 16;
  return __builtin_bit_cast(float, u);
}
static __device__ __forceinline__ unsigned short f2bf(float f) {
  unsigned int u = __builtin_bit_cast(unsigned int, f);
  u += 0x7FFFu + ((u >> 16) & 1u);   // RNE
  return (unsigned short)(u >> 16);
}
static __device__ __forceinline__ float ldsc(const void* p, int i, int fm) {
  return fm ? ((const float*)p)[i] : bf2f(((const unsigned short*)p)[i]);
}
static __device__ __forceinline__ float i2f(int v) { return __builtin_bit_cast(float, v); }
static __device__ __forceinline__ void split8r(f32x4 u0, f32x4 u1, bf16x8& hi, bf16x8& lo) {
  #pragma unroll
  for (int j = 0; j < 4; ++j) {
    float v0 = u0[j], v1 = u1[j];
    __bf16 h0 = (__bf16)v0, h1 = (__bf16)v1;
    hi[j] = h0;     lo[j] = (__bf16)(v0 - (float)h0);
    hi[4 + j] = h1; lo[4 + j] = (__bf16)(v1 - (float)h1);
  }
}
static __device__ __forceinline__ void splitsc(float v, unsigned short* hp, unsigned short* lp) {
  __bf16 h = (__bf16)v;
  *hp = __builtin_bit_cast(unsigned short, h);
  __bf16 l = (__bf16)(v - (float)h);
  *lp = __builtin_bit_cast(unsigned short, l);
}

// ---------------- dtype probe ----------------
__global__ void k_probe(const unsigned short* __restrict__ xs,
                        const int* __restrict__ ei, int* __restrict__ flags) {
  __shared__ int cnt_big, cnt_nz;
  if (threadIdx.x == 0) { cnt_big = 0; cnt_nz = 0; }
  __syncthreads();
  unsigned short u = xs[threadIdx.x];
  int expf = (u >> 7) & 0xFF;
  if (expf >= 0x8D) atomicAdd(&cnt_big, 1);
  if (threadIdx.x < 128 && ei[2 * threadIdx.x + 1] != 0) atomicAdd(&cnt_nz, 1);
  __syncthreads();
  if (threadIdx.x == 0) {
    flags[0] = (cnt_big >= 2) ? 1 : 0;
    flags[1] = (cnt_nz < 64) ? 1 : 0;
  }
}

// ---------------- weight pre-split ----------------
__global__ void k_wsplit(const void* __restrict__ Wv, const int* __restrict__ flags,
                         int n, unsigned short* __restrict__ hi,
                         unsigned short* __restrict__ lo) {
  int i = blockIdx.x * 256 + threadIdx.x;
  if (i >= n) return;
  float v = ldsc(Wv, i, flags[0]);
  splitsc(v, hi + i, lo + i);
}

// ---------------- graph build ----------------
__global__ void k_deg(const int* __restrict__ ei, const int* __restrict__ flags,
                      int* __restrict__ deg) {
  int e = blockIdx.x * 256 + threadIdx.x;
  if (e >= EE) return;
  int r, c;
  if (flags[1]) { r = ((const int2*)ei)[e].x; c = ((const int2*)ei)[EE + e].x; }
  else          { r = ei[e];                  c = ei[EE + e]; }
  if (r != c) { atomicAdd(&deg[r], 1); atomicAdd(&deg[c], 1); }
}

__global__ void k_chunksum(const int* __restrict__ deg, int* __restrict__ csum) {
  __shared__ int sd[1024];
  int i = blockIdx.x * 1024 + threadIdx.x;
  sd[threadIdx.x] = (i < NN) ? deg[i] : 0;
  __syncthreads();
  for (int s = 512; s > 0; s >>= 1) {
    if (threadIdx.x < s) sd[threadIdx.x] += sd[threadIdx.x + s];
    __syncthreads();
  }
  if (threadIdx.x == 0) csum[blockIdx.x] = sd[0];
}

__global__ void k_scanchunks(int* __restrict__ csum, int* __restrict__ total) {
  if (threadIdx.x == 0) {
    int acc = 0;
    for (int i = 0; i < NCH; ++i) { int v = csum[i]; csum[i] = acc; acc += v; }
    total[0] = acc;
  }
}

__global__ void k_offs(const int* __restrict__ deg, const int* __restrict__ cbase,
                       int* __restrict__ offs, float* __restrict__ dinv) {
  __shared__ int sd[1024];
  int i = blockIdx.x * 1024 + threadIdx.x;
  int v = (i < NN) ? deg[i] : 0;
  sd[threadIdx.x] = v;
  __syncthreads();
  for (int s = 1; s < 1024; s <<= 1) {
    int t = (threadIdx.x >= s) ? sd[threadIdx.x - s] : 0;
    __syncthreads();
    sd[threadIdx.x] += t;
    __syncthreads();
  }
  if (i < NN) {
    offs[i] = cbase[blockIdx.x] + sd[threadIdx.x] - v;
    dinv[i] = (v > 0) ? rsqrtf((float)v) : 0.f;
  }
}

__global__ void k_fill(const int* __restrict__ ei, const int* __restrict__ flags,
                       const int* __restrict__ offs,
                       int* __restrict__ fill, const float* __restrict__ dinv,
                       int2* __restrict__ ep) {
  int e = blockIdx.x * 256 + threadIdx.x;
  if (e >= EE) return;
  int r, c;
  if (flags[1]) { r = ((const int2*)ei)[e].x; c = ((const int2*)ei)[EE + e].x; }
  else          { r = ei[e];                  c = ei[EE + e]; }
  if (r == c) return;
  float w = dinv[r] * dinv[c];
  int wb = __builtin_bit_cast(int, w);
  int p = offs[r] + atomicAdd(&fill[r], 1);
  ep[p] = make_int2(c, wb);
  int q = offs[c] + atomicAdd(&fill[c], 1);
  ep[q] = make_int2(r, wb);
}

// ---------------- embed GEMM: hb = bf16(relu(x @ W^T + b)), + BN stats -------
// Round 7/8: 256 threads = 4 independent waves; each wave computes 16 rows x
// full K=512 into acc[4] (16 VGPRs). No K-split, no sacc LDS, no barrier in
// the GEMM -> register headroom for pipelined loads + high occupancy.
// BN partials: 2 KB LDS block reduction, then 64+64 atomics per block.
__global__ __launch_bounds__(256, 4) void k_embed(
    const void* __restrict__ xv,
    const unsigned short* __restrict__ whi, const unsigned short* __restrict__ wlo,
    const void* __restrict__ bEv, const int* __restrict__ flags,
    unsigned short* __restrict__ hb, float* __restrict__ bnsum, float* __restrict__ bnsq) {
  __shared__ float ssum[4][64];
  __shared__ float ssq[4][64];
  const int fm = flags[0];
  const int wave = threadIdx.x >> 6, lane = threadIdx.x & 63;
  const int l15 = lane & 15, quad = lane >> 4;
  const int rb = blockIdx.x * 64 + wave * 16;
  int rowl = rb + l15; if (rowl > NN - 1) rowl = NN - 1;
  f32x4 acc[4] = {};
  if (fm) {
    const float* xr = (const float*)xv + (size_t)rowl * IND + quad * 8;
    for (int kk = 0; kk < 16; ++kk) {
      f32x4 u0 = *(const f32x4*)(xr + kk * 32);
      f32x4 u1 = *(const f32x4*)(xr + kk * 32 + 4);
      bf16x8 ahi, alo;
      split8r(u0, u1, ahi, alo);
      #pragma unroll
      for (int nt = 0; nt < 4; ++nt) {
        size_t wb = (size_t)(nt * 16 + l15) * IND + kk * 32 + quad * 8;
        bf16x8 bhi = *(const bf16x8*)(whi + wb);
        bf16x8 blo = *(const bf16x8*)(wlo + wb);
        acc[nt] = __builtin_amdgcn_mfma_f32_16x16x32_bf16(ahi, bhi, acc[nt], 0, 0, 0);
        acc[nt] = __builtin_amdgcn_mfma_f32_16x16x32_bf16(alo, bhi, acc[nt], 0, 0, 0);
        acc[nt] = __builtin_amdgcn_mfma_f32_16x16x32_bf16(ahi, blo, acc[nt], 0, 0, 0);
      }
    }
  } else {
    const unsigned short* xr = (const unsigned short*)xv + (size_t)rowl * IND + quad * 8;
    #pragma unroll 2
    for (int kk = 0; kk < 16; ++kk) {
      bf16x8 a = *(const bf16x8*)(xr + kk * 32);
      #pragma unroll
      for (int nt = 0; nt < 4; ++nt) {
        bf16x8 bhi = *(const bf16x8*)(whi + (size_t)(nt * 16 + l15) * IND + kk * 32 + quad * 8);
        acc[nt] = __builtin_amdgcn_mfma_f32_16x16x32_bf16(a, bhi, acc[nt], 0, 0, 0);
      }
    }
  }
  // epilogue: bias + relu + store hb + per-wave BN partials (from registers)
  #pragma unroll
  for (int nt = 0; nt < 4; ++nt) {
    int n = nt * 16 + l15;
    float bb = ldsc(bEv, n, fm);
    float ps = 0.f, pq = 0.f;
    #pragma unroll
    for (int r = 0; r < 4; ++r) {
      int row = rb + quad * 4 + r;
      if (row < NN) {
        float v = fmaxf(acc[nt][r] + bb, 0.f);
        hb[(size_t)row * 64 + n] = f2bf(v);
        ps += v; pq += v * v;
      }
    }
    ps += __shfl_xor(ps, 16); pq += __shfl_xor(pq, 16);
    ps += __shfl_xor(ps, 32); pq += __shfl_xor(pq, 32);
    if (quad == 0) { ssum[wave][n] = ps; ssq[wave][n] = pq; }
  }
  __syncthreads();
  if (threadIdx.x < 64) {
    int c = threadIdx.x;
    float s = ssum[0][c] + ssum[1][c] + ssum[2][c] + ssum[3][c];
    float q = ssq[0][c] + ssq[1][c] + ssq[2][c] + ssq[3][c];
    atomicAdd(&bnsum[c], s);
    atomicAdd(&bnsq[c], q);
  }
}

__global__ void k_bnfin(const float* __restrict__ bnsum, const float* __restrict__ bnsq,
                        const void* __restrict__ gv, const void* __restrict__ bv,
                        const int* __restrict__ flags, float* __restrict__ ab) {
  int c = threadIdx.x;
  int fm = flags[0];
  if (c < 64) {
    float mu = bnsum[c] * (1.0f / (float)NN);
    float var = bnsq[c] * (1.0f / (float)NN) - mu * mu;
    float a = ldsc(gv, c, fm) / sqrtf(var + 1e-5f);
    float b = ldsc(bv, c, fm) - mu * a;
    ab[c] = a; ab[64 + c] = b;
  }
}

// ---------------- SPMM: x8 gather of bf16 tables ----------------
#define GATHER8(SRC, STRIDE)                                                   \
  float a[8] = {}; float sw = 0, sq = 0; (void)sw; (void)sq;                   \
  int j = s;                                                                   \
  for (; j + 8 <= e; j += 8) {                                                 \
    int2 p[8];                                                                 \
    _Pragma("unroll") for (int t = 0; t < 8; ++t) p[t] = ep[j + t];            \
    float xv[8];                                                               \
    _Pragma("unroll") for (int t = 0; t < 8; ++t)                              \
      xv[t] = bf2f(SRC[(size_t)p[t].x * STRIDE + lane]);                       \
    _Pragma("unroll") for (int t = 0; t < 8; ++t) {                            \
      float w = i2f(p[t].y);                                                   \
      a[t] = fmaf(w, xv[t], a[t]); sw += w; sq = fmaf(w, w, sq);               \
    }                                                                          \
  }                                                                            \
  for (; j < e; ++j) {                                                         \
    int2 p = ep[j]; float w = i2f(p.y);                                        \
    a[0] = fmaf(w, bf2f(SRC[(size_t)p.x * STRIDE + lane]), a[0]);              \
    sw += w; sq = fmaf(w, w, sq);                                              \
  }                                                                            \
  float acc = ((a[0] + a[1]) + (a[2] + a[3])) + ((a[4] + a[5]) + (a[6] + a[7]));

// SPMM1: gather hb; block0 = BN(hb[r]); block1 = h1; diag2 = Sum(w^2)
__global__ __launch_bounds__(256) void k_sp1(
    const int* __restrict__ offs, const int2* __restrict__ ep,
    const unsigned short* __restrict__ hb, const float* __restrict__ bnab,
    float* __restrict__ diag2,
    unsigned short* __restrict__ zhi, unsigned short* __restrict__ zlo) {
  const int r = blockIdx.x * 4 + (threadIdx.x >> 6);
  const int lane = threadIdx.x & 63;
  if (r >= NN) return;
  int s = offs[r], e = offs[r + 1];
  GATHER8(hb, 64)
  float ga = bnab[lane], gb = bnab[64 + lane];
  size_t zr = (size_t)r * ZD;
  float z0 = fmaf(ga, bf2f(hb[(size_t)r * 64 + lane]), gb);
  float h1 = ga * acc + gb * sw;
  splitsc(z0, zhi + zr + lane, zlo + zr + lane);
  splitsc(h1, zhi + zr + 64 + lane, zlo + zr + 64 + lane);
  if (lane == 0) diag2[r] = sq;
}

// SPMM2: gather block1; h2 = acc - diag2*z0; block2 = h2; curb = bf16(h1+h2)
__global__ __launch_bounds__(256) void k_sp2(
    const int* __restrict__ offs, const int2* __restrict__ ep,
    const float* __restrict__ diag2,
    unsigned short* __restrict__ zhi, unsigned short* __restrict__ zlo,
    unsigned short* __restrict__ curb) {
  const int r = blockIdx.x * 4 + (threadIdx.x >> 6);
  const int lane = threadIdx.x & 63;
  if (r >= NN) return;
  int s = offs[r], e = offs[r + 1];
  const unsigned short* src = zhi + 64;
  GATHER8(src, ZD)
  size_t zr = (size_t)r * ZD;
  float z0 = bf2f(zhi[zr + lane]) + bf2f(zlo[zr + lane]);
  float h1 = bf2f(zhi[zr + 64 + lane]) + bf2f(zlo[zr + 64 + lane]);
  float h2 = acc - diag2[r] * z0;
  splitsc(h2, zhi + zr + 128 + lane, zlo + zr + 128 + lane);
  curb[(size_t)r * 64 + lane] = f2bf(h1 + h2);
}

// SPMM3/4: gather src (stride ss); y = acc [- diag2*bf(corrb)]; block zoff = y
__global__ __launch_bounds__(256) void k_spg(
    const int* __restrict__ offs, const int2* __restrict__ ep,
    const unsigned short* __restrict__ src, long ss,
    const float* __restrict__ diag2, const unsigned short* __restrict__ corrb,
    unsigned short* __restrict__ zhi, unsigned short* __restrict__ zlo, long zoff) {
  const int r = blockIdx.x * 4 + (threadIdx.x >> 6);
  const int lane = threadIdx.x & 63;
  if (r >= NN) return;
  int s = offs[r], e = offs[r + 1];
  GATHER8(src, ss)
  if (corrb) acc -= diag2[r] * bf2f(corrb[(size_t)r * 64 + lane]);
  size_t zi = (size_t)r * ZD + zoff + lane;
  splitsc(acc, zhi + zi, zlo + zi);
}

// ---------------- final: out = relu(z @ W1^T + b1) @ W2^T + b2 ----------------
// M=32/wave; A-frags loaded directly from pre-split zhi/zlo (no VALU split).
__global__ __launch_bounds__(256) void k_final(
    const unsigned short* __restrict__ zhi, const unsigned short* __restrict__ zlo,
    const unsigned short* __restrict__ w1hi, const unsigned short* __restrict__ w1lo,
    const void* __restrict__ b1v,
    const unsigned short* __restrict__ w2hi, const unsigned short* __restrict__ w2lo,
    const void* __restrict__ b2v,
    const int* __restrict__ flags, void* __restrict__ outv) {
  __shared__ float tls[4][2][16][68];
  const int fm = flags[0];
  const int wave = threadIdx.x >> 6, lane = threadIdx.x & 63;
  const int l15 = lane & 15, quad = lane >> 4;
  const int gid = blockIdx.x * 4 + wave;      // 0..3124 valid (32 rows each)
  const bool valid = gid < NN / 32;
  if (valid) {
    const int rb = gid * 32;
    f32x4 acc[2][4] = {};
    size_t zb[2];
    #pragma unroll
    for (int t = 0; t < 2; ++t)
      zb[t] = (size_t)(rb + t * 16 + l15) * ZD + quad * 8;
    for (int ks = 0; ks < 10; ++ks) {
      bf16x8 ahi[2], alo[2];
      #pragma unroll
      for (int t = 0; t < 2; ++t) {
        ahi[t] = *(const bf16x8*)(zhi + zb[t] + ks * 32);
        alo[t] = *(const bf16x8*)(zlo + zb[t] + ks * 32);
      }
      #pragma unroll
      for (int nt = 0; nt < 4; ++nt) {
        size_t wb = (size_t)(nt * 16 + l15) * ZD + ks * 32 + quad * 8;
        bf16x8 bhi = *(const bf16x8*)(w1hi + wb);
        bf16x8 blo = *(const bf16x8*)(w1lo + wb);
        #pragma unroll
        for (int t = 0; t < 2; ++t) {
          acc[t][nt] = __builtin_amdgcn_mfma_f32_16x16x32_bf16(ahi[t], bhi, acc[t][nt], 0, 0, 0);
          acc[t][nt] = __builtin_amdgcn_mfma_f32_16x16x32_bf16(alo[t], bhi, acc[t][nt], 0, 0, 0);
          acc[t][nt] = __builtin_amdgcn_mfma_f32_16x16x32_bf16(ahi[t], blo, acc[t][nt], 0, 0, 0);
        }
      }
    }
    #pragma unroll
    for (int nt = 0; nt < 4; ++nt) {
      int n = nt * 16 + l15;
      float bb = ldsc(b1v, n, fm);
      #pragma unroll
      for (int t = 0; t < 2; ++t)
        #pragma unroll
        for (int r = 0; r < 4; ++r)
          tls[wave][t][quad * 4 + r][n] = fmaxf(acc[t][nt][r] + bb, 0.f);
    }
  }
  __syncthreads();
  if (valid) {
    const int rb = gid * 32;
    f32x4 acc2[2][3] = {};
    #pragma unroll
    for (int ks = 0; ks < 2; ++ks) {
      bf16x8 ahi[2], alo[2];
      #pragma unroll
      for (int t = 0; t < 2; ++t)
        #pragma unroll
        for (int j = 0; j < 8; ++j) {
          float v = tls[wave][t][l15][ks * 32 + quad * 8 + j];
          __bf16 h = (__bf16)v;
          ahi[t][j] = h; alo[t][j] = (__bf16)(v - (float)h);
        }
      #pragma unroll
      for (int nt = 0; nt < 3; ++nt) {
        int n = nt * 16 + l15;
        bf16x8 bhi = {}, blo = {};
        if (n < CLS) {
          size_t wb = (size_t)n * HID + ks * 32 + quad * 8;
          bhi = *(const bf16x8*)(w2hi + wb);
          blo = *(const bf16x8*)(w2lo + wb);
        }
        #pragma unroll
        for (int t = 0; t < 2; ++t) {
          acc2[t][nt] = __builtin_amdgcn_mfma_f32_16x16x32_bf16(ahi[t], bhi, acc2[t][nt], 0, 0, 0);
          acc2[t][nt] = __builtin_amdgcn_mfma_f32_16x16x32_bf16(alo[t], bhi, acc2[t][nt], 0, 0, 0);
          acc2[t][nt] = __builtin_amdgcn_mfma_f32_16x16x32_bf16(ahi[t], blo, acc2[t][nt], 0, 0, 0);
        }
      }
    }
    #pragma unroll
    for (int nt = 0; nt < 3; ++nt) {
      int n = nt * 16 + l15;
      if (n < CLS) {
        float bb = ldsc(b2v, n, fm);
        #pragma unroll
        for (int t = 0; t < 2; ++t)
          #pragma unroll
          for (int r = 0; r < 4; ++r) {
            float v = acc2[t][nt][r] + bb;
            size_t oi = (size_t)(rb + t * 16 + quad * 4 + r) * CLS + n;
            if (fm) ((float*)outv)[oi] = v;
            else    ((unsigned short*)outv)[oi] = f2bf(v);
          }
      }
    }
  }
}

extern "C" void kernel_launch(void* const* d_in, const int* in_sizes, int n_in,
                              void* d_out, int out_size, void* d_ws, size_t ws_size,
                              hipStream_t stream) {
  (void)in_sizes; (void)n_in; (void)out_size; (void)ws_size;
  const void* x   = d_in[0];
  const int*  ei  = (const int*)d_in[1];
  const void* WE  = d_in[2];
  const void* bE  = d_in[3];
  const void* gam = d_in[4];
  const void* bet = d_in[5];
  const void* W1  = d_in[6];
  const void* b1  = d_in[7];
  const void* W2  = d_in[8];
  const void* b2  = d_in[9];

  float* wsf = (float*)d_ws;
  int*   wsi = (int*)d_ws;
  // word-offset layout; total ~168.6 MB (same as round 5)
  int*   deg   = wsi + 0;          // NN (zeroed)
  int*   fill  = wsi + 100000;     // NN (zeroed)
  float* bnsum = wsf + 200000;     // 64 (zeroed)
  float* bnsq  = wsf + 200064;     // 64 (zeroed)
  int*   flags = wsi + 200128;     // 8
  float* bnab  = wsf + 200136;     // 128
  float* dinv  = wsf + 200264;     // NN
  int*   offs  = wsi + 300264;     // NN+1
  int*   cbase = wsi + 400272;     // NCH (pad to 400384)
  unsigned short* whi  = (unsigned short*)(wsi + 400384);  // 64*512
  unsigned short* wlo  = (unsigned short*)(wsi + 416768);
  unsigned short* w1hi = (unsigned short*)(wsi + 433152);  // 64*320
  unsigned short* w1lo = (unsigned short*)(wsi + 443392);
  unsigned short* w2hi = (unsigned short*)(wsi + 453632);  // 40*64
  unsigned short* w2lo = (unsigned short*)(wsi + 454912);
  int2*  ep    = (int2*)(wsi + 456192);   // 1.6M edges
  float* diag2 = wsf + 3656192;    // NN
  unsigned short* hb   = (unsigned short*)(wsi + 3756192);  // NN*64 bf16
  unsigned short* curb = (unsigned short*)(wsi + 6956192);  // NN*64 bf16
  unsigned short* zhi  = (unsigned short*)(wsi + 10156192); // NN*320 bf16
  unsigned short* zlo  = (unsigned short*)(wsi + 26156192); // NN*320 bf16

  hipMemsetAsync(d_ws, 0, (size_t)200128 * 4, stream);

  k_probe     <<<1, 256, 0, stream>>>((const unsigned short*)x, ei, flags);
  k_wsplit    <<<(64 * IND + 255) / 256, 256, 0, stream>>>(WE, flags, 64 * IND, whi, wlo);
  k_wsplit    <<<(64 * ZD + 255) / 256, 256, 0, stream>>>(W1, flags, 64 * ZD, w1hi, w1lo);
  k_wsplit    <<<(CLS * HID + 255) / 256, 256, 0, stream>>>(W2, flags, CLS * HID, w2hi, w2lo);

  k_deg       <<<EE / 256, 256, 0, stream>>>(ei, flags, deg);
  k_chunksum  <<<NCH, 1024, 0, stream>>>(deg, cbase);
  k_scanchunks<<<1, 64, 0, stream>>>(cbase, offs + NN);
  k_offs      <<<NCH, 1024, 0, stream>>>(deg, cbase, offs, dinv);
  k_fill      <<<EE / 256, 256, 0, stream>>>(ei, flags, offs, fill, dinv, ep);

  k_embed     <<<NBLK, 256, 0, stream>>>(x, whi, wlo, bE, flags, hb, bnsum, bnsq);
  k_bnfin     <<<1, 64, 0, stream>>>(bnsum, bnsq, gam, bet, flags, bnab);

  k_sp1<<<NN / 4, 256, 0, stream>>>(offs, ep, hb, bnab, diag2, zhi, zlo);
  k_sp2<<<NN / 4, 256, 0, stream>>>(offs, ep, diag2, zhi, zlo, curb);
  k_spg<<<NN / 4, 256, 0, stream>>>(offs, ep, curb, 64, diag2, nullptr, zhi, zlo, 192);
  k_spg<<<NN / 4, 256, 0, stream>>>(offs, ep, zhi + 192, ZD, diag2, curb, zhi, zlo, 256);

  k_final<<<(NN / 32 + 3) / 4, 256, 0, stream>>>(zhi, zlo, w1hi, w1lo, b1,
                                                 w2hi, w2lo, b2, flags, d_out);
}

// Round 3
// 845.292 us; speedup vs baseline: 1.0876x; 1.0876x over previous
//
#include <hip/hip_runtime.h>
#include <stdint.h>

// H2GCN forward on MI355X (gfx950). Round 9:
//  - r8 post-mortem: M=16/wave quadrupled W traffic and compiler kept only 36
//    VGPRs (no pipelining) -> slower despite 2x occupancy. Latency-bound on
//    x loads (no prefetch) + W loads (64B-useful-per-line pattern).
//  - k_embed v9: M=32 rows/wave (acc=32 VGPR), W pre-packed in MFMA-fragment
//    order (k_wpack; 1KB fully-coalesced L2 reads), manual 1-deep x prefetch
//    (double-buffered regs) to keep ~12 loads in flight per wave.
//  - Packed W planes reuse dead deg/fill workspace (after k_fill).
//  - SPMMs / k_final unchanged (isolate the experiment).

typedef __bf16 bf16x8 __attribute__((ext_vector_type(8)));
typedef float  f32x4  __attribute__((ext_vector_type(4)));

#define NN   100000
#define EE   800000
#define IND  512
#define HID  64
#define ZD   320
#define CLS  40
#define NCH  98           // ceil(NN/1024)
#define NBLKE 782         // ceil(NN/128) embed blocks (4 waves x 32 rows)

static __device__ __forceinline__ float bf2f(unsigned short s) {
  unsigned int u = ((unsigned int)s) << 16;
  return __builtin_bit_cast(float, u);
}
static __device__ __forceinline__ unsigned short f2bf(float f) {
  unsigned int u = __builtin_bit_cast(unsigned int, f);
  u += 0x7FFFu + ((u >> 16) & 1u);   // RNE
  return (unsigned short)(u >> 16);
}
static __device__ __forceinline__ float ldsc(const void* p, int i, int fm) {
  return fm ? ((const float*)p)[i] : bf2f(((const unsigned short*)p)[i]);
}
static __device__ __forceinline__ float i2f(int v) { return __builtin_bit_cast(float, v); }
static __device__ __forceinline__ void split8r(f32x4 u0, f32x4 u1, bf16x8& hi, bf16x8& lo) {
  #pragma unroll
  for (int j = 0; j < 4; ++j) {
    float v0 = u0[j], v1 = u1[j];
    __bf16 h0 = (__bf16)v0, h1 = (__bf16)v1;
    hi[j] = h0;     lo[j] = (__bf16)(v0 - (float)h0);
    hi[4 + j] = h1; lo[4 + j] = (__bf16)(v1 - (float)h1);
  }
}
static __device__ __forceinline__ void splitsc(float v, unsigned short* hp, unsigned short* lp) {
  __bf16 h = (__bf16)v;
  *hp = __builtin_bit_cast(unsigned short, h);
  __bf16 l = (__bf16)(v - (float)h);
  *lp = __builtin_bit_cast(unsigned short, l);
}

// ---------------- dtype probe ----------------
__global__ void k_probe(const unsigned short* __restrict__ xs,
                        const int* __restrict__ ei, int* __restrict__ flags) {
  __shared__ int cnt_big, cnt_nz;
  if (threadIdx.x == 0) { cnt_big = 0; cnt_nz = 0; }
  __syncthreads();
  unsigned short u = xs[threadIdx.x];
  int expf = (u >> 7) & 0xFF;
  if (expf >= 0x8D) atomicAdd(&cnt_big, 1);
  if (threadIdx.x < 128 && ei[2 * threadIdx.x + 1] != 0) atomicAdd(&cnt_nz, 1);
  __syncthreads();
  if (threadIdx.x == 0) {
    flags[0] = (cnt_big >= 2) ? 1 : 0;
    flags[1] = (cnt_nz < 64) ? 1 : 0;
  }
}

// ---------------- weight pre-split (W1, W2) ----------------
__global__ void k_wsplit(const void* __restrict__ Wv, const int* __restrict__ flags,
                         int n, unsigned short* __restrict__ hi,
                         unsigned short* __restrict__ lo) {
  int i = blockIdx.x * 256 + threadIdx.x;
  if (i >= n) return;
  float v = ldsc(Wv, i, flags[0]);
  splitsc(v, hi + i, lo + i);
}

// ---------------- embed-W split + pack into MFMA fragment order -------------
// Fragment f = kk*4+nt holds B-operand for col-tile nt at k-step kk.
// lane reads WE[(nt*16+l15)*512 + kk*32 + quad*8 .. +8]; packed dst is
// contiguous: ph[(f*64+lane)*8 .. +8] -> k_embed W loads = coalesced 1KB.
__global__ void k_wpack(const void* __restrict__ Wv, const int* __restrict__ flags,
                        unsigned short* __restrict__ ph, unsigned short* __restrict__ pl) {
  int tid = blockIdx.x * 256 + threadIdx.x;
  if (tid >= 64 * 64) return;
  int f = tid >> 6, lane = tid & 63;
  int kk = f >> 2, nt = f & 3;
  int l15 = lane & 15, quad = lane >> 4;
  int fmv = flags[0];
  int src = (nt * 16 + l15) * IND + kk * 32 + quad * 8;
  size_t dst = ((size_t)f * 64 + lane) * 8;
  #pragma unroll
  for (int j = 0; j < 8; ++j) {
    float v = ldsc(Wv, src + j, fmv);
    splitsc(v, ph + dst + j, pl + dst + j);
  }
}

// ---------------- graph build ----------------
__global__ void k_deg(const int* __restrict__ ei, const int* __restrict__ flags,
                      int* __restrict__ deg) {
  int e = blockIdx.x * 256 + threadIdx.x;
  if (e >= EE) return;
  int r, c;
  if (flags[1]) { r = ((const int2*)ei)[e].x; c = ((const int2*)ei)[EE + e].x; }
  else          { r = ei[e];                  c = ei[EE + e]; }
  if (r != c) { atomicAdd(&deg[r], 1); atomicAdd(&deg[c], 1); }
}

__global__ void k_chunksum(const int* __restrict__ deg, int* __restrict__ csum) {
  __shared__ int sd[1024];
  int i = blockIdx.x * 1024 + threadIdx.x;
  sd[threadIdx.x] = (i < NN) ? deg[i] : 0;
  __syncthreads();
  for (int s = 512; s > 0; s >>= 1) {
    if (threadIdx.x < s) sd[threadIdx.x] += sd[threadIdx.x + s];
    __syncthreads();
  }
  if (threadIdx.x == 0) csum[blockIdx.x] = sd[0];
}

__global__ void k_scanchunks(int* __restrict__ csum, int* __restrict__ total) {
  if (threadIdx.x == 0) {
    int acc = 0;
    for (int i = 0; i < NCH; ++i) { int v = csum[i]; csum[i] = acc; acc += v; }
    total[0] = acc;
  }
}

__global__ void k_offs(const int* __restrict__ deg, const int* __restrict__ cbase,
                       int* __restrict__ offs, float* __restrict__ dinv) {
  __shared__ int sd[1024];
  int i = blockIdx.x * 1024 + threadIdx.x;
  int v = (i < NN) ? deg[i] : 0;
  sd[threadIdx.x] = v;
  __syncthreads();
  for (int s = 1; s < 1024; s <<= 1) {
    int t = (threadIdx.x >= s) ? sd[threadIdx.x - s] : 0;
    __syncthreads();
    sd[threadIdx.x] += t;
    __syncthreads();
  }
  if (i < NN) {
    offs[i] = cbase[blockIdx.x] + sd[threadIdx.x] - v;
    dinv[i] = (v > 0) ? rsqrtf((float)v) : 0.f;
  }
}

__global__ void k_fill(const int* __restrict__ ei, const int* __restrict__ flags,
                       const int* __restrict__ offs,
                       int* __restrict__ fill, const float* __restrict__ dinv,
                       int2* __restrict__ ep) {
  int e = blockIdx.x * 256 + threadIdx.x;
  if (e >= EE) return;
  int r, c;
  if (flags[1]) { r = ((const int2*)ei)[e].x; c = ((const int2*)ei)[EE + e].x; }
  else          { r = ei[e];                  c = ei[EE + e]; }
  if (r == c) return;
  float w = dinv[r] * dinv[c];
  int wb = __builtin_bit_cast(int, w);
  int p = offs[r] + atomicAdd(&fill[r], 1);
  ep[p] = make_int2(c, wb);
  int q = offs[c] + atomicAdd(&fill[c], 1);
  ep[q] = make_int2(r, wb);
}

// ---------------- embed GEMM: hb = bf16(relu(x @ W^T + b)), + BN stats -------
// v9: 4 waves/block, each wave = 32 rows x full K=512, acc[2][4] (32 VGPR).
// W loads from packed fragments (coalesced 1KB, L2-resident); x loads manually
// prefetched 1 iteration ahead (double-buffered regs) for memory parallelism.
__global__ __launch_bounds__(256, 4) void k_embed(
    const void* __restrict__ xv,
    const unsigned short* __restrict__ wph, const unsigned short* __restrict__ wpl,
    const void* __restrict__ bEv, const int* __restrict__ flags,
    unsigned short* __restrict__ hb, float* __restrict__ bnsum, float* __restrict__ bnsq) {
  __shared__ float ssum[4][64];
  __shared__ float ssq[4][64];
  const int fm = flags[0];
  const int wave = threadIdx.x >> 6, lane = threadIdx.x & 63;
  const int l15 = lane & 15, quad = lane >> 4;
  const int rb = blockIdx.x * 128 + wave * 32;
  int row0 = rb + l15;      if (row0 > NN - 1) row0 = NN - 1;
  int row1 = rb + 16 + l15; if (row1 > NN - 1) row1 = NN - 1;
  f32x4 acc[2][4] = {};
  if (fm) {
    const float* xr0 = (const float*)xv + (size_t)row0 * IND + quad * 8;
    const float* xr1 = (const float*)xv + (size_t)row1 * IND + quad * 8;
    f32x4 u0[2][2], u1[2][2];
    u0[0][0] = *(const f32x4*)(xr0);  u1[0][0] = *(const f32x4*)(xr0 + 4);
    u0[0][1] = *(const f32x4*)(xr1);  u1[0][1] = *(const f32x4*)(xr1 + 4);
    for (int kk = 0; kk < 16; ++kk) {
      const int cur = kk & 1, nxt = cur ^ 1;
      if (kk < 15) {   // prefetch next k-step's x (issues before this step's MFMAs)
        u0[nxt][0] = *(const f32x4*)(xr0 + (kk + 1) * 32);
        u1[nxt][0] = *(const f32x4*)(xr0 + (kk + 1) * 32 + 4);
        u0[nxt][1] = *(const f32x4*)(xr1 + (kk + 1) * 32);
        u1[nxt][1] = *(const f32x4*)(xr1 + (kk + 1) * 32 + 4);
      }
      bf16x8 bh[4], bl[4];
      #pragma unroll
      for (int nt = 0; nt < 4; ++nt) {
        size_t off = ((size_t)(kk * 4 + nt) * 64 + lane) * 8;
        bh[nt] = *(const bf16x8*)(wph + off);
        bl[nt] = *(const bf16x8*)(wpl + off);
      }
      #pragma unroll
      for (int t = 0; t < 2; ++t) {
        bf16x8 ahi, alo;
        split8r(u0[cur][t], u1[cur][t], ahi, alo);
        #pragma unroll
        for (int nt = 0; nt < 4; ++nt) {
          acc[t][nt] = __builtin_amdgcn_mfma_f32_16x16x32_bf16(ahi, bh[nt], acc[t][nt], 0, 0, 0);
          acc[t][nt] = __builtin_amdgcn_mfma_f32_16x16x32_bf16(alo, bh[nt], acc[t][nt], 0, 0, 0);
          acc[t][nt] = __builtin_amdgcn_mfma_f32_16x16x32_bf16(ahi, bl[nt], acc[t][nt], 0, 0, 0);
        }
      }
    }
  } else {
    const unsigned short* xr0 = (const unsigned short*)xv + (size_t)row0 * IND + quad * 8;
    const unsigned short* xr1 = (const unsigned short*)xv + (size_t)row1 * IND + quad * 8;
    for (int kk = 0; kk < 16; ++kk) {
      bf16x8 bh[4];
      #pragma unroll
      for (int nt = 0; nt < 4; ++nt)
        bh[nt] = *(const bf16x8*)(wph + ((size_t)(kk * 4 + nt) * 64 + lane) * 8);
      bf16x8 a0 = *(const bf16x8*)(xr0 + kk * 32);
      bf16x8 a1 = *(const bf16x8*)(xr1 + kk * 32);
      #pragma unroll
      for (int nt = 0; nt < 4; ++nt) {
        acc[0][nt] = __builtin_amdgcn_mfma_f32_16x16x32_bf16(a0, bh[nt], acc[0][nt], 0, 0, 0);
        acc[1][nt] = __builtin_amdgcn_mfma_f32_16x16x32_bf16(a1, bh[nt], acc[1][nt], 0, 0, 0);
      }
    }
  }
  // epilogue: bias + relu + store hb + per-wave BN partials (from registers)
  #pragma unroll
  for (int nt = 0; nt < 4; ++nt) {
    int n = nt * 16 + l15;
    float bb = ldsc(bEv, n, fm);
    float ps = 0.f, pq = 0.f;
    #pragma unroll
    for (int t = 0; t < 2; ++t)
      #pragma unroll
      for (int r = 0; r < 4; ++r) {
        int row = rb + t * 16 + quad * 4 + r;
        if (row < NN) {
          float v = fmaxf(acc[t][nt][r] + bb, 0.f);
          hb[(size_t)row * 64 + n] = f2bf(v);
          ps += v; pq += v * v;
        }
      }
    ps += __shfl_xor(ps, 16); pq += __shfl_xor(pq, 16);
    ps += __shfl_xor(ps, 32); pq += __shfl_xor(pq, 32);
    if (quad == 0) { ssum[wave][n] = ps; ssq[wave][n] = pq; }
  }
  __syncthreads();
  if (threadIdx.x < 64) {
    int c = threadIdx.x;
    float s = ssum[0][c] + ssum[1][c] + ssum[2][c] + ssum[3][c];
    float q = ssq[0][c] + ssq[1][c] + ssq[2][c] + ssq[3][c];
    atomicAdd(&bnsum[c], s);
    atomicAdd(&bnsq[c], q);
  }
}

__global__ void k_bnfin(const float* __restrict__ bnsum, const float* __restrict__ bnsq,
                        const void* __restrict__ gv, const void* __restrict__ bv,
                        const int* __restrict__ flags, float* __restrict__ ab) {
  int c = threadIdx.x;
  int fm = flags[0];
  if (c < 64) {
    float mu = bnsum[c] * (1.0f / (float)NN);
    float var = bnsq[c] * (1.0f / (float)NN) - mu * mu;
    float a = ldsc(gv, c, fm) / sqrtf(var + 1e-5f);
    float b = ldsc(bv, c, fm) - mu * a;
    ab[c] = a; ab[64 + c] = b;
  }
}

// ---------------- SPMM: x8 gather of bf16 tables ----------------
#define GATHER8(SRC, STRIDE)                                                   \
  float a[8] = {}; float sw = 0, sq = 0; (void)sw; (void)sq;                   \
  int j = s;                                                                   \
  for (; j + 8 <= e; j += 8) {                                                 \
    int2 p[8];                                                                 \
    _Pragma("unroll") for (int t = 0; t < 8; ++t) p[t] = ep[j + t];            \
    float xv[8];                                                               \
    _Pragma("unroll") for (int t = 0; t < 8; ++t)                              \
      xv[t] = bf2f(SRC[(size_t)p[t].x * STRIDE + lane]);                       \
    _Pragma("unroll") for (int t = 0; t < 8; ++t) {                            \
      float w = i2f(p[t].y);                                                   \
      a[t] = fmaf(w, xv[t], a[t]); sw += w; sq = fmaf(w, w, sq);               \
    }                                                                          \
  }                                                                            \
  for (; j < e; ++j) {                                                         \
    int2 p = ep[j]; float w = i2f(p.y);                                        \
    a[0] = fmaf(w, bf2f(SRC[(size_t)p.x * STRIDE + lane]), a[0]);              \
    sw += w; sq = fmaf(w, w, sq);                                              \
  }                                                                            \
  float acc = ((a[0] + a[1]) + (a[2] + a[3])) + ((a[4] + a[5]) + (a[6] + a[7]));

// SPMM1: gather hb; block0 = BN(hb[r]); block1 = h1; diag2 = Sum(w^2)
__global__ __launch_bounds__(256) void k_sp1(
    const int* __restrict__ offs, const int2* __restrict__ ep,
    const unsigned short* __restrict__ hb, const float* __restrict__ bnab,
    float* __restrict__ diag2,
    unsigned short* __restrict__ zhi, unsigned short* __restrict__ zlo) {
  const int r = blockIdx.x * 4 + (threadIdx.x >> 6);
  const int lane = threadIdx.x & 63;
  if (r >= NN) return;
  int s = offs[r], e = offs[r + 1];
  GATHER8(hb, 64)
  float ga = bnab[lane], gb = bnab[64 + lane];
  size_t zr = (size_t)r * ZD;
  float z0 = fmaf(ga, bf2f(hb[(size_t)r * 64 + lane]), gb);
  float h1 = ga * acc + gb * sw;
  splitsc(z0, zhi + zr + lane, zlo + zr + lane);
  splitsc(h1, zhi + zr + 64 + lane, zlo + zr + 64 + lane);
  if (lane == 0) diag2[r] = sq;
}

// SPMM2: gather block1; h2 = acc - diag2*z0; block2 = h2; curb = bf16(h1+h2)
__global__ __launch_bounds__(256) void k_sp2(
    const int* __restrict__ offs, const int2* __restrict__ ep,
    const float* __restrict__ diag2,
    unsigned short* __restrict__ zhi, unsigned short* __restrict__ zlo,
    unsigned short* __restrict__ curb) {
  const int r = blockIdx.x * 4 + (threadIdx.x >> 6);
  const int lane = threadIdx.x & 63;
  if (r >= NN) return;
  int s = offs[r], e = offs[r + 1];
  const unsigned short* src = zhi + 64;
  GATHER8(src, ZD)
  size_t zr = (size_t)r * ZD;
  float z0 = bf2f(zhi[zr + lane]) + bf2f(zlo[zr + lane]);
  float h1 = bf2f(zhi[zr + 64 + lane]) + bf2f(zlo[zr + 64 + lane]);
  float h2 = acc - diag2[r] * z0;
  splitsc(h2, zhi + zr + 128 + lane, zlo + zr + 128 + lane);
  curb[(size_t)r * 64 + lane] = f2bf(h1 + h2);
}

// SPMM3/4: gather src (stride ss); y = acc [- diag2*bf(corrb)]; block zoff = y
__global__ __launch_bounds__(256) void k_spg(
    const int* __restrict__ offs, const int2* __restrict__ ep,
    const unsigned short* __restrict__ src, long ss,
    const float* __restrict__ diag2, const unsigned short* __restrict__ corrb,
    unsigned short* __restrict__ zhi, unsigned short* __restrict__ zlo, long zoff) {
  const int r = blockIdx.x * 4 + (threadIdx.x >> 6);
  const int lane = threadIdx.x & 63;
  if (r >= NN) return;
  int s = offs[r], e = offs[r + 1];
  GATHER8(src, ss)
  if (corrb) acc -= diag2[r] * bf2f(corrb[(size_t)r * 64 + lane]);
  size_t zi = (size_t)r * ZD + zoff + lane;
  splitsc(acc, zhi + zi, zlo + zi);
}

// ---------------- final: out = relu(z @ W1^T + b1) @ W2^T + b2 ----------------
// M=32/wave; A-frags loaded directly from pre-split zhi/zlo (no VALU split).
__global__ __launch_bounds__(256) void k_final(
    const unsigned short* __restrict__ zhi, const unsigned short* __restrict__ zlo,
    const unsigned short* __restrict__ w1hi, const unsigned short* __restrict__ w1lo,
    const void* __restrict__ b1v,
    const unsigned short* __restrict__ w2hi, const unsigned short* __restrict__ w2lo,
    const void* __restrict__ b2v,
    const int* __restrict__ flags, void* __restrict__ outv) {
  __shared__ float tls[4][2][16][68];
  const int fm = flags[0];
  const int wave = threadIdx.x >> 6, lane = threadIdx.x & 63;
  const int l15 = lane & 15, quad = lane >> 4;
  const int gid = blockIdx.x * 4 + wave;      // 0..3124 valid (32 rows each)
  const bool valid = gid < NN / 32;
  if (valid) {
    const int rb = gid * 32;
    f32x4 acc[2][4] = {};
    size_t zb[2];
    #pragma unroll
    for (int t = 0; t < 2; ++t)
      zb[t] = (size_t)(rb + t * 16 + l15) * ZD + quad * 8;
    for (int ks = 0; ks < 10; ++ks) {
      bf16x8 ahi[2], alo[2];
      #pragma unroll
      for (int t = 0; t < 2; ++t) {
        ahi[t] = *(const bf16x8*)(zhi + zb[t] + ks * 32);
        alo[t] = *(const bf16x8*)(zlo + zb[t] + ks * 32);
      }
      #pragma unroll
      for (int nt = 0; nt < 4; ++nt) {
        size_t wb = (size_t)(nt * 16 + l15) * ZD + ks * 32 + quad * 8;
        bf16x8 bhi = *(const bf16x8*)(w1hi + wb);
        bf16x8 blo = *(const bf16x8*)(w1lo + wb);
        #pragma unroll
        for (int t = 0; t < 2; ++t) {
          acc[t][nt] = __builtin_amdgcn_mfma_f32_16x16x32_bf16(ahi[t], bhi, acc[t][nt], 0, 0, 0);
          acc[t][nt] = __builtin_amdgcn_mfma_f32_16x16x32_bf16(alo[t], bhi, acc[t][nt], 0, 0, 0);
          acc[t][nt] = __builtin_amdgcn_mfma_f32_16x16x32_bf16(ahi[t], blo, acc[t][nt], 0, 0, 0);
        }
      }
    }
    #pragma unroll
    for (int nt = 0; nt < 4; ++nt) {
      int n = nt * 16 + l15;
      float bb = ldsc(b1v, n, fm);
      #pragma unroll
      for (int t = 0; t < 2; ++t)
        #pragma unroll
        for (int r = 0; r < 4; ++r)
          tls[wave][t][quad * 4 + r][n] = fmaxf(acc[t][nt][r] + bb, 0.f);
    }
  }
  __syncthreads();
  if (valid) {
    const int rb = gid * 32;
    f32x4 acc2[2][3] = {};
    #pragma unroll
    for (int ks = 0; ks < 2; ++ks) {
      bf16x8 ahi[2], alo[2];
      #pragma unroll
      for (int t = 0; t < 2; ++t)
        #pragma unroll
        for (int j = 0; j < 8; ++j) {
          float v = tls[wave][t][l15][ks * 32 + quad * 8 + j];
          __bf16 h = (__bf16)v;
          ahi[t][j] = h; alo[t][j] = (__bf16)(v - (float)h);
        }
      #pragma unroll
      for (int nt = 0; nt < 3; ++nt) {
        int n = nt * 16 + l15;
        bf16x8 bhi = {}, blo = {};
        if (n < CLS) {
          size_t wb = (size_t)n * HID + ks * 32 + quad * 8;
          bhi = *(const bf16x8*)(w2hi + wb);
          blo = *(const bf16x8*)(w2lo + wb);
        }
        #pragma unroll
        for (int t = 0; t < 2; ++t) {
          acc2[t][nt] = __builtin_amdgcn_mfma_f32_16x16x32_bf16(ahi[t], bhi, acc2[t][nt], 0, 0, 0);
          acc2[t][nt] = __builtin_amdgcn_mfma_f32_16x16x32_bf16(alo[t], bhi, acc2[t][nt], 0, 0, 0);
          acc2[t][nt] = __builtin_amdgcn_mfma_f32_16x16x32_bf16(ahi[t], blo, acc2[t][nt], 0, 0, 0);
        }
      }
    }
    #pragma unroll
    for (int nt = 0; nt < 3; ++nt) {
      int n = nt * 16 + l15;
      if (n < CLS) {
        float bb = ldsc(b2v, n, fm);
        #pragma unroll
        for (int t = 0; t < 2; ++t)
          #pragma unroll
          for (int r = 0; r < 4; ++r) {
            float v = acc2[t][nt][r] + bb;
            size_t oi = (size_t)(rb + t * 16 + quad * 4 + r) * CLS + n;
            if (fm) ((float*)outv)[oi] = v;
            else    ((unsigned short*)outv)[oi] = f2bf(v);
          }
      }
    }
  }
}

extern "C" void kernel_launch(void* const* d_in, const int* in_sizes, int n_in,
                              void* d_out, int out_size, void* d_ws, size_t ws_size,
                              hipStream_t stream) {
  (void)in_sizes; (void)n_in; (void)out_size; (void)ws_size;
  const void* x   = d_in[0];
  const int*  ei  = (const int*)d_in[1];
  const void* WE  = d_in[2];
  const void* bE  = d_in[3];
  const void* gam = d_in[4];
  const void* bet = d_in[5];
  const void* W1  = d_in[6];
  const void* b1  = d_in[7];
  const void* W2  = d_in[8];
  const void* b2  = d_in[9];

  float* wsf = (float*)d_ws;
  int*   wsi = (int*)d_ws;
  // word-offset layout; total ~168.6 MB (same as round 5)
  int*   deg   = wsi + 0;          // NN (zeroed)
  int*   fill  = wsi + 100000;     // NN (zeroed)
  float* bnsum = wsf + 200000;     // 64 (zeroed)
  float* bnsq  = wsf + 200064;     // 64 (zeroed)
  int*   flags = wsi + 200128;     // 8
  float* bnab  = wsf + 200136;     // 128
  float* dinv  = wsf + 200264;     // NN
  int*   offs  = wsi + 300264;     // NN+1
  int*   cbase = wsi + 400272;     // NCH (pad to 400384)
  unsigned short* w1hi = (unsigned short*)(wsi + 433152);  // 64*320
  unsigned short* w1lo = (unsigned short*)(wsi + 443392);
  unsigned short* w2hi = (unsigned short*)(wsi + 453632);  // 40*64
  unsigned short* w2lo = (unsigned short*)(wsi + 454912);
  int2*  ep    = (int2*)(wsi + 456192);   // 1.6M edges
  float* diag2 = wsf + 3656192;    // NN
  unsigned short* hb   = (unsigned short*)(wsi + 3756192);  // NN*64 bf16
  unsigned short* curb = (unsigned short*)(wsi + 6956192);  // NN*64 bf16
  unsigned short* zhi  = (unsigned short*)(wsi + 10156192); // NN*320 bf16
  unsigned short* zlo  = (unsigned short*)(wsi + 26156192); // NN*320 bf16
  // packed embed-W planes (64 KB each) reuse deg/fill, which are dead after
  // k_fill; k_wpack launches after k_fill.
  unsigned short* wph  = (unsigned short*)(wsi + 0);       // 64*512 bf16 hi
  unsigned short* wpl  = (unsigned short*)(wsi + 100000);  // 64*512 bf16 lo

  hipMemsetAsync(d_ws, 0, (size_t)200128 * 4, stream);

  k_probe     <<<1, 256, 0, stream>>>((const unsigned short*)x, ei, flags);
  k_wsplit    <<<(64 * ZD + 255) / 256, 256, 0, stream>>>(W1, flags, 64 * ZD, w1hi, w1lo);
  k_wsplit    <<<(CLS * HID + 255) / 256, 256, 0, stream>>>(W2, flags, CLS * HID, w2hi, w2lo);

  k_deg       <<<EE / 256, 256, 0, stream>>>(ei, flags, deg);
  k_chunksum  <<<NCH, 1024, 0, stream>>>(deg, cbase);
  k_scanchunks<<<1, 64, 0, stream>>>(cbase, offs + NN);
  k_offs      <<<NCH, 1024, 0, stream>>>(deg, cbase, offs, dinv);
  k_fill      <<<EE / 256, 256, 0, stream>>>(ei, flags, offs, fill, dinv, ep);

  k_wpack     <<<16, 256, 0, stream>>>(WE, flags, wph, wpl);
  k_embed     <<<NBLKE, 256, 0, stream>>>(x, wph, wpl, bE, flags, hb, bnsum, bnsq);
  k_bnfin     <<<1, 64, 0, stream>>>(bnsum, bnsq, gam, bet, flags, bnab);

  k_sp1<<<NN / 4, 256, 0, stream>>>(offs, ep, hb, bnab, diag2, zhi, zlo);
  k_sp2<<<NN / 4, 256, 0, stream>>>(offs, ep, diag2, zhi, zlo, curb);
  k_spg<<<NN / 4, 256, 0, stream>>>(offs, ep, curb, 64, diag2, nullptr, zhi, zlo, 192);
  k_spg<<<NN / 4, 256, 0, stream>>>(offs, ep, zhi + 192, ZD, diag2, curb, zhi, zlo, 256);

  k_final<<<(NN / 32 + 3) / 4, 256, 0, stream>>>(zhi, zlo, w1hi, w1lo, b1,
                                                 w2hi, w2lo, b2, flags, d_out);
}

// Round 4
// 829.219 us; speedup vs baseline: 1.1087x; 1.0194x over previous
//
#include <hip/hip_runtime.h>
#include <stdint.h>

// H2GCN forward on MI355X (gfx950). Round 10:
//  - r9 post-mortem: compiler sank the register prefetch (VGPR=48) -> still
//    latency-serialized. Fix: stage x through LDS with global_load_lds
//    (fire-and-forget, cannot be sunk), 2-phase double-buffered chunks.
//  - XOR swizzle (both-sides: pre-swizzled global source + swizzled read)
//    kills the 16-way bank conflict of the 256B-row layout.
//  - W loads issued before stage ops (sched_barrier pinned) so compiler can
//    wait them with vmcnt(4) without draining the in-flight staging.
//  - SPMMs / k_final unchanged.

typedef __bf16 bf16x8 __attribute__((ext_vector_type(8)));
typedef float  f32x4  __attribute__((ext_vector_type(4)));

#define NN   100000
#define EE   800000
#define IND  512
#define HID  64
#define ZD   320
#define CLS  40
#define NCH  98           // ceil(NN/1024)
#define NBLKE 1563        // ceil(NN/64) embed blocks (4 waves x 16 rows)

static __device__ __forceinline__ float bf2f(unsigned short s) {
  unsigned int u = ((unsigned int)s) << 16;
  return __builtin_bit_cast(float, u);
}
static __device__ __forceinline__ unsigned short f2bf(float f) {
  unsigned int u = __builtin_bit_cast(unsigned int, f);
  u += 0x7FFFu + ((u >> 16) & 1u);   // RNE
  return (unsigned short)(u >> 16);
}
static __device__ __forceinline__ float ldsc(const void* p, int i, int fm) {
  return fm ? ((const float*)p)[i] : bf2f(((const unsigned short*)p)[i]);
}
static __device__ __forceinline__ float i2f(int v) { return __builtin_bit_cast(float, v); }
static __device__ __forceinline__ void split8r(f32x4 u0, f32x4 u1, bf16x8& hi, bf16x8& lo) {
  #pragma unroll
  for (int j = 0; j < 4; ++j) {
    float v0 = u0[j], v1 = u1[j];
    __bf16 h0 = (__bf16)v0, h1 = (__bf16)v1;
    hi[j] = h0;     lo[j] = (__bf16)(v0 - (float)h0);
    hi[4 + j] = h1; lo[4 + j] = (__bf16)(v1 - (float)h1);
  }
}
static __device__ __forceinline__ void splitsc(float v, unsigned short* hp, unsigned short* lp) {
  __bf16 h = (__bf16)v;
  *hp = __builtin_bit_cast(unsigned short, h);
  __bf16 l = (__bf16)(v - (float)h);
  *lp = __builtin_bit_cast(unsigned short, l);
}
// async global->LDS, 16B per lane (dest = uniform base + lane*16)
static __device__ __forceinline__ void gload16(const void* g, void* l) {
  __builtin_amdgcn_global_load_lds(
      (const __attribute__((address_space(1))) void*)g,
      (__attribute__((address_space(3))) void*)l, 16, 0, 0);
}

// ---------------- dtype probe ----------------
__global__ void k_probe(const unsigned short* __restrict__ xs,
                        const int* __restrict__ ei, int* __restrict__ flags) {
  __shared__ int cnt_big, cnt_nz;
  if (threadIdx.x == 0) { cnt_big = 0; cnt_nz = 0; }
  __syncthreads();
  unsigned short u = xs[threadIdx.x];
  int expf = (u >> 7) & 0xFF;
  if (expf >= 0x8D) atomicAdd(&cnt_big, 1);
  if (threadIdx.x < 128 && ei[2 * threadIdx.x + 1] != 0) atomicAdd(&cnt_nz, 1);
  __syncthreads();
  if (threadIdx.x == 0) {
    flags[0] = (cnt_big >= 2) ? 1 : 0;
    flags[1] = (cnt_nz < 64) ? 1 : 0;
  }
}

// ---------------- weight pre-split (W1, W2) ----------------
__global__ void k_wsplit(const void* __restrict__ Wv, const int* __restrict__ flags,
                         int n, unsigned short* __restrict__ hi,
                         unsigned short* __restrict__ lo) {
  int i = blockIdx.x * 256 + threadIdx.x;
  if (i >= n) return;
  float v = ldsc(Wv, i, flags[0]);
  splitsc(v, hi + i, lo + i);
}

// ---------------- embed-W split + pack into MFMA fragment order -------------
__global__ void k_wpack(const void* __restrict__ Wv, const int* __restrict__ flags,
                        unsigned short* __restrict__ ph, unsigned short* __restrict__ pl) {
  int tid = blockIdx.x * 256 + threadIdx.x;
  if (tid >= 64 * 64) return;
  int f = tid >> 6, lane = tid & 63;
  int kk = f >> 2, nt = f & 3;
  int l15 = lane & 15, quad = lane >> 4;
  int fmv = flags[0];
  int src = (nt * 16 + l15) * IND + kk * 32 + quad * 8;
  size_t dst = ((size_t)f * 64 + lane) * 8;
  #pragma unroll
  for (int j = 0; j < 8; ++j) {
    float v = ldsc(Wv, src + j, fmv);
    splitsc(v, ph + dst + j, pl + dst + j);
  }
}

// ---------------- graph build ----------------
__global__ void k_deg(const int* __restrict__ ei, const int* __restrict__ flags,
                      int* __restrict__ deg) {
  int e = blockIdx.x * 256 + threadIdx.x;
  if (e >= EE) return;
  int r, c;
  if (flags[1]) { r = ((const int2*)ei)[e].x; c = ((const int2*)ei)[EE + e].x; }
  else          { r = ei[e];                  c = ei[EE + e]; }
  if (r != c) { atomicAdd(&deg[r], 1); atomicAdd(&deg[c], 1); }
}

__global__ void k_chunksum(const int* __restrict__ deg, int* __restrict__ csum) {
  __shared__ int sd[1024];
  int i = blockIdx.x * 1024 + threadIdx.x;
  sd[threadIdx.x] = (i < NN) ? deg[i] : 0;
  __syncthreads();
  for (int s = 512; s > 0; s >>= 1) {
    if (threadIdx.x < s) sd[threadIdx.x] += sd[threadIdx.x + s];
    __syncthreads();
  }
  if (threadIdx.x == 0) csum[blockIdx.x] = sd[0];
}

__global__ void k_scanchunks(int* __restrict__ csum, int* __restrict__ total) {
  if (threadIdx.x == 0) {
    int acc = 0;
    for (int i = 0; i < NCH; ++i) { int v = csum[i]; csum[i] = acc; acc += v; }
    total[0] = acc;
  }
}

__global__ void k_offs(const int* __restrict__ deg, const int* __restrict__ cbase,
                       int* __restrict__ offs, float* __restrict__ dinv) {
  __shared__ int sd[1024];
  int i = blockIdx.x * 1024 + threadIdx.x;
  int v = (i < NN) ? deg[i] : 0;
  sd[threadIdx.x] = v;
  __syncthreads();
  for (int s = 1; s < 1024; s <<= 1) {
    int t = (threadIdx.x >= s) ? sd[threadIdx.x - s] : 0;
    __syncthreads();
    sd[threadIdx.x] += t;
    __syncthreads();
  }
  if (i < NN) {
    offs[i] = cbase[blockIdx.x] + sd[threadIdx.x] - v;
    dinv[i] = (v > 0) ? rsqrtf((float)v) : 0.f;
  }
}

__global__ void k_fill(const int* __restrict__ ei, const int* __restrict__ flags,
                       const int* __restrict__ offs,
                       int* __restrict__ fill, const float* __restrict__ dinv,
                       int2* __restrict__ ep) {
  int e = blockIdx.x * 256 + threadIdx.x;
  if (e >= EE) return;
  int r, c;
  if (flags[1]) { r = ((const int2*)ei)[e].x; c = ((const int2*)ei)[EE + e].x; }
  else          { r = ei[e];                  c = ei[EE + e]; }
  if (r == c) return;
  float w = dinv[r] * dinv[c];
  int wb = __builtin_bit_cast(int, w);
  int p = offs[r] + atomicAdd(&fill[r], 1);
  ep[p] = make_int2(c, wb);
  int q = offs[c] + atomicAdd(&fill[c], 1);
  ep[q] = make_int2(r, wb);
}

// ---------------- embed GEMM: hb = bf16(relu(x @ W^T + b)), + BN stats -------
// v10: block = 4 waves x 16 rows = 64 rows. x staged into LDS in 8
// double-buffered 16KB chunks via global_load_lds (async, can't be sunk by
// the compiler). XOR swizzle (pre-swizzled global src + swizzled read) makes
// the 256B-row chunk conflict-free. W frag loads issued BEFORE the stage ops
// (sched_barrier pinned) so MFMA waits use vmcnt(4), not a full drain.
__global__ __launch_bounds__(256, 4) void k_embed(
    const void* __restrict__ xv,
    const unsigned short* __restrict__ wph, const unsigned short* __restrict__ wpl,
    const void* __restrict__ bEv, const int* __restrict__ flags,
    unsigned short* __restrict__ hb, float* __restrict__ bnsum, float* __restrict__ bnsq) {
  __shared__ char xb[2][16384] __attribute__((aligned(128)));
  __shared__ float ssum[4][64];
  __shared__ float ssq[4][64];
  const int fm = flags[0];
  const int wave = threadIdx.x >> 6, lane = threadIdx.x & 63;
  const int l15 = lane & 15, quad = lane >> 4;
  const int rb = blockIdx.x * 64;
  const int rbw = rb + wave * 16;
  f32x4 acc[4] = {};
  if (fm) {
    // per-lane global source pointers for this wave's 4 staging instructions.
    // stage instr I covers LDS bytes [I*1024,(I+1)*1024); lane l writes LDS
    // byte I*1024+l*16 which must hold row = I*4+quad, borig = (l15^(quad&1))*16
    const char* sp[4];
    {
      const int borig = (l15 ^ (quad & 1)) * 16;
      #pragma unroll
      for (int j = 0; j < 4; ++j) {
        int grow = rb + (wave * 4 + j) * 4 + quad;
        if (grow > NN - 1) grow = NN - 1;
        sp[j] = (const char*)xv + (size_t)grow * 2048 + borig;
      }
    }
    // swizzled read offsets: row-local = wave*16+l15, parity p = l15&1
    const int p = l15 & 1;
    const int roA = (wave * 16 + l15) * 256 + quad * 32 + 16 * p;        // orig [b0,b0+16)
    const int roB = (wave * 16 + l15) * 256 + quad * 32 + 16 - 16 * p;   // orig [b0+16,b0+32)
    // prologue: stage chunk 0 into buf 0
    #pragma unroll
    for (int j = 0; j < 4; ++j)
      gload16(sp[j], &xb[0][(wave * 4 + j) * 1024]);
    __syncthreads();
    for (int c = 0; c < 8; ++c) {
      const int cur = c & 1;
      // 1) W fragments for this chunk (2 k-steps) -> regs, BEFORE the stage
      bf16x8 bh[2][4], bl[2][4];
      #pragma unroll
      for (int ks = 0; ks < 2; ++ks)
        #pragma unroll
        for (int nt = 0; nt < 4; ++nt) {
          size_t off = ((size_t)((c * 2 + ks) * 4 + nt) * 64 + lane) * 8;
          bh[ks][nt] = *(const bf16x8*)(wph + off);
          bl[ks][nt] = *(const bf16x8*)(wpl + off);
        }
      __builtin_amdgcn_sched_barrier(0);
      // 2) async stage of next chunk (drained by the end-of-chunk barrier)
      if (c < 7) {
        char* db = &xb[cur ^ 1][0];
        #pragma unroll
        for (int j = 0; j < 4; ++j)
          gload16(sp[j] + (c + 1) * 256, db + (wave * 4 + j) * 1024);
      }
      __builtin_amdgcn_sched_barrier(0);
      // 3) compute chunk c from LDS
      const char* cb = &xb[cur][0];
      #pragma unroll
      for (int ks = 0; ks < 2; ++ks) {
        f32x4 u0 = *(const f32x4*)(cb + roA + ks * 128);
        f32x4 u1 = *(const f32x4*)(cb + roB + ks * 128);
        bf16x8 ahi, alo;
        split8r(u0, u1, ahi, alo);
        #pragma unroll
        for (int nt = 0; nt < 4; ++nt) {
          acc[nt] = __builtin_amdgcn_mfma_f32_16x16x32_bf16(ahi, bh[ks][nt], acc[nt], 0, 0, 0);
          acc[nt] = __builtin_amdgcn_mfma_f32_16x16x32_bf16(alo, bh[ks][nt], acc[nt], 0, 0, 0);
          acc[nt] = __builtin_amdgcn_mfma_f32_16x16x32_bf16(ahi, bl[ks][nt], acc[nt], 0, 0, 0);
        }
      }
      __syncthreads();   // drains stage (vmcnt 0) + orders buffer reuse
    }
  } else {
    int row0 = rbw + l15; if (row0 > NN - 1) row0 = NN - 1;
    const unsigned short* xr0 = (const unsigned short*)xv + (size_t)row0 * IND + quad * 8;
    for (int kk = 0; kk < 16; ++kk) {
      bf16x8 bh[4];
      #pragma unroll
      for (int nt = 0; nt < 4; ++nt)
        bh[nt] = *(const bf16x8*)(wph + ((size_t)(kk * 4 + nt) * 64 + lane) * 8);
      bf16x8 a0 = *(const bf16x8*)(xr0 + kk * 32);
      #pragma unroll
      for (int nt = 0; nt < 4; ++nt)
        acc[nt] = __builtin_amdgcn_mfma_f32_16x16x32_bf16(a0, bh[nt], acc[nt], 0, 0, 0);
    }
  }
  // epilogue: bias + relu + store hb + per-wave BN partials (from registers)
  #pragma unroll
  for (int nt = 0; nt < 4; ++nt) {
    int n = nt * 16 + l15;
    float bb = ldsc(bEv, n, fm);
    float ps = 0.f, pq = 0.f;
    #pragma unroll
    for (int r = 0; r < 4; ++r) {
      int row = rbw + quad * 4 + r;
      if (row < NN) {
        float v = fmaxf(acc[nt][r] + bb, 0.f);
        hb[(size_t)row * 64 + n] = f2bf(v);
        ps += v; pq += v * v;
      }
    }
    ps += __shfl_xor(ps, 16); pq += __shfl_xor(pq, 16);
    ps += __shfl_xor(ps, 32); pq += __shfl_xor(pq, 32);
    if (quad == 0) { ssum[wave][n] = ps; ssq[wave][n] = pq; }
  }
  __syncthreads();
  if (threadIdx.x < 64) {
    int c = threadIdx.x;
    float s = ssum[0][c] + ssum[1][c] + ssum[2][c] + ssum[3][c];
    float q = ssq[0][c] + ssq[1][c] + ssq[2][c] + ssq[3][c];
    atomicAdd(&bnsum[c], s);
    atomicAdd(&bnsq[c], q);
  }
}

__global__ void k_bnfin(const float* __restrict__ bnsum, const float* __restrict__ bnsq,
                        const void* __restrict__ gv, const void* __restrict__ bv,
                        const int* __restrict__ flags, float* __restrict__ ab) {
  int c = threadIdx.x;
  int fm = flags[0];
  if (c < 64) {
    float mu = bnsum[c] * (1.0f / (float)NN);
    float var = bnsq[c] * (1.0f / (float)NN) - mu * mu;
    float a = ldsc(gv, c, fm) / sqrtf(var + 1e-5f);
    float b = ldsc(bv, c, fm) - mu * a;
    ab[c] = a; ab[64 + c] = b;
  }
}

// ---------------- SPMM: x8 gather of bf16 tables ----------------
#define GATHER8(SRC, STRIDE)                                                   \
  float a[8] = {}; float sw = 0, sq = 0; (void)sw; (void)sq;                   \
  int j = s;                                                                   \
  for (; j + 8 <= e; j += 8) {                                                 \
    int2 p[8];                                                                 \
    _Pragma("unroll") for (int t = 0; t < 8; ++t) p[t] = ep[j + t];            \
    float xv[8];                                                               \
    _Pragma("unroll") for (int t = 0; t < 8; ++t)                              \
      xv[t] = bf2f(SRC[(size_t)p[t].x * STRIDE + lane]);                       \
    _Pragma("unroll") for (int t = 0; t < 8; ++t) {                            \
      float w = i2f(p[t].y);                                                   \
      a[t] = fmaf(w, xv[t], a[t]); sw += w; sq = fmaf(w, w, sq);               \
    }                                                                          \
  }                                                                            \
  for (; j < e; ++j) {                                                         \
    int2 p = ep[j]; float w = i2f(p.y);                                        \
    a[0] = fmaf(w, bf2f(SRC[(size_t)p.x * STRIDE + lane]), a[0]);              \
    sw += w; sq = fmaf(w, w, sq);                                              \
  }                                                                            \
  float acc = ((a[0] + a[1]) + (a[2] + a[3])) + ((a[4] + a[5]) + (a[6] + a[7]));

// SPMM1: gather hb; block0 = BN(hb[r]); block1 = h1; diag2 = Sum(w^2)
__global__ __launch_bounds__(256) void k_sp1(
    const int* __restrict__ offs, const int2* __restrict__ ep,
    const unsigned short* __restrict__ hb, const float* __restrict__ bnab,
    float* __restrict__ diag2,
    unsigned short* __restrict__ zhi, unsigned short* __restrict__ zlo) {
  const int r = blockIdx.x * 4 + (threadIdx.x >> 6);
  const int lane = threadIdx.x & 63;
  if (r >= NN) return;
  int s = offs[r], e = offs[r + 1];
  GATHER8(hb, 64)
  float ga = bnab[lane], gb = bnab[64 + lane];
  size_t zr = (size_t)r * ZD;
  float z0 = fmaf(ga, bf2f(hb[(size_t)r * 64 + lane]), gb);
  float h1 = ga * acc + gb * sw;
  splitsc(z0, zhi + zr + lane, zlo + zr + lane);
  splitsc(h1, zhi + zr + 64 + lane, zlo + zr + 64 + lane);
  if (lane == 0) diag2[r] = sq;
}

// SPMM2: gather block1; h2 = acc - diag2*z0; block2 = h2; curb = bf16(h1+h2)
__global__ __launch_bounds__(256) void k_sp2(
    const int* __restrict__ offs, const int2* __restrict__ ep,
    const float* __restrict__ diag2,
    unsigned short* __restrict__ zhi, unsigned short* __restrict__ zlo,
    unsigned short* __restrict__ curb) {
  const int r = blockIdx.x * 4 + (threadIdx.x >> 6);
  const int lane = threadIdx.x & 63;
  if (r >= NN) return;
  int s = offs[r], e = offs[r + 1];
  const unsigned short* src = zhi + 64;
  GATHER8(src, ZD)
  size_t zr = (size_t)r * ZD;
  float z0 = bf2f(zhi[zr + lane]) + bf2f(zlo[zr + lane]);
  float h1 = bf2f(zhi[zr + 64 + lane]) + bf2f(zlo[zr + 64 + lane]);
  float h2 = acc - diag2[r] * z0;
  splitsc(h2, zhi + zr + 128 + lane, zlo + zr + 128 + lane);
  curb[(size_t)r * 64 + lane] = f2bf(h1 + h2);
}

// SPMM3/4: gather src (stride ss); y = acc [- diag2*bf(corrb)]; block zoff = y
__global__ __launch_bounds__(256) void k_spg(
    const int* __restrict__ offs, const int2* __restrict__ ep,
    const unsigned short* __restrict__ src, long ss,
    const float* __restrict__ diag2, const unsigned short* __restrict__ corrb,
    unsigned short* __restrict__ zhi, unsigned short* __restrict__ zlo, long zoff) {
  const int r = blockIdx.x * 4 + (threadIdx.x >> 6);
  const int lane = threadIdx.x & 63;
  if (r >= NN) return;
  int s = offs[r], e = offs[r + 1];
  GATHER8(src, ss)
  if (corrb) acc -= diag2[r] * bf2f(corrb[(size_t)r * 64 + lane]);
  size_t zi = (size_t)r * ZD + zoff + lane;
  splitsc(acc, zhi + zi, zlo + zi);
}

// ---------------- final: out = relu(z @ W1^T + b1) @ W2^T + b2 ----------------
__global__ __launch_bounds__(256) void k_final(
    const unsigned short* __restrict__ zhi, const unsigned short* __restrict__ zlo,
    const unsigned short* __restrict__ w1hi, const unsigned short* __restrict__ w1lo,
    const void* __restrict__ b1v,
    const unsigned short* __restrict__ w2hi, const unsigned short* __restrict__ w2lo,
    const void* __restrict__ b2v,
    const int* __restrict__ flags, void* __restrict__ outv) {
  __shared__ float tls[4][2][16][68];
  const int fm = flags[0];
  const int wave = threadIdx.x >> 6, lane = threadIdx.x & 63;
  const int l15 = lane & 15, quad = lane >> 4;
  const int gid = blockIdx.x * 4 + wave;      // 0..3124 valid (32 rows each)
  const bool valid = gid < NN / 32;
  if (valid) {
    const int rb = gid * 32;
    f32x4 acc[2][4] = {};
    size_t zb[2];
    #pragma unroll
    for (int t = 0; t < 2; ++t)
      zb[t] = (size_t)(rb + t * 16 + l15) * ZD + quad * 8;
    for (int ks = 0; ks < 10; ++ks) {
      bf16x8 ahi[2], alo[2];
      #pragma unroll
      for (int t = 0; t < 2; ++t) {
        ahi[t] = *(const bf16x8*)(zhi + zb[t] + ks * 32);
        alo[t] = *(const bf16x8*)(zlo + zb[t] + ks * 32);
      }
      #pragma unroll
      for (int nt = 0; nt < 4; ++nt) {
        size_t wb = (size_t)(nt * 16 + l15) * ZD + ks * 32 + quad * 8;
        bf16x8 bhi = *(const bf16x8*)(w1hi + wb);
        bf16x8 blo = *(const bf16x8*)(w1lo + wb);
        #pragma unroll
        for (int t = 0; t < 2; ++t) {
          acc[t][nt] = __builtin_amdgcn_mfma_f32_16x16x32_bf16(ahi[t], bhi, acc[t][nt], 0, 0, 0);
          acc[t][nt] = __builtin_amdgcn_mfma_f32_16x16x32_bf16(alo[t], bhi, acc[t][nt], 0, 0, 0);
          acc[t][nt] = __builtin_amdgcn_mfma_f32_16x16x32_bf16(ahi[t], blo, acc[t][nt], 0, 0, 0);
        }
      }
    }
    #pragma unroll
    for (int nt = 0; nt < 4; ++nt) {
      int n = nt * 16 + l15;
      float bb = ldsc(b1v, n, fm);
      #pragma unroll
      for (int t = 0; t < 2; ++t)
        #pragma unroll
        for (int r = 0; r < 4; ++r)
          tls[wave][t][quad * 4 + r][n] = fmaxf(acc[t][nt][r] + bb, 0.f);
    }
  }
  __syncthreads();
  if (valid) {
    const int rb = gid * 32;
    f32x4 acc2[2][3] = {};
    #pragma unroll
    for (int ks = 0; ks < 2; ++ks) {
      bf16x8 ahi[2], alo[2];
      #pragma unroll
      for (int t = 0; t < 2; ++t)
        #pragma unroll
        for (int j = 0; j < 8; ++j) {
          float v = tls[wave][t][l15][ks * 32 + quad * 8 + j];
          __bf16 h = (__bf16)v;
          ahi[t][j] = h; alo[t][j] = (__bf16)(v - (float)h);
        }
      #pragma unroll
      for (int nt = 0; nt < 3; ++nt) {
        int n = nt * 16 + l15;
        bf16x8 bhi = {}, blo = {};
        if (n < CLS) {
          size_t wb = (size_t)n * HID + ks * 32 + quad * 8;
          bhi = *(const bf16x8*)(w2hi + wb);
          blo = *(const bf16x8*)(w2lo + wb);
        }
        #pragma unroll
        for (int t = 0; t < 2; ++t) {
          acc2[t][nt] = __builtin_amdgcn_mfma_f32_16x16x32_bf16(ahi[t], bhi, acc2[t][nt], 0, 0, 0);
          acc2[t][nt] = __builtin_amdgcn_mfma_f32_16x16x32_bf16(alo[t], bhi, acc2[t][nt], 0, 0, 0);
          acc2[t][nt] = __builtin_amdgcn_mfma_f32_16x16x32_bf16(ahi[t], blo, acc2[t][nt], 0, 0, 0);
        }
      }
    }
    #pragma unroll
    for (int nt = 0; nt < 3; ++nt) {
      int n = nt * 16 + l15;
      if (n < CLS) {
        float bb = ldsc(b2v, n, fm);
        #pragma unroll
        for (int t = 0; t < 2; ++t)
          #pragma unroll
          for (int r = 0; r < 4; ++r) {
            float v = acc2[t][nt][r] + bb;
            size_t oi = (size_t)(rb + t * 16 + quad * 4 + r) * CLS + n;
            if (fm) ((float*)outv)[oi] = v;
            else    ((unsigned short*)outv)[oi] = f2bf(v);
          }
      }
    }
  }
}

extern "C" void kernel_launch(void* const* d_in, const int* in_sizes, int n_in,
                              void* d_out, int out_size, void* d_ws, size_t ws_size,
                              hipStream_t stream) {
  (void)in_sizes; (void)n_in; (void)out_size; (void)ws_size;
  const void* x   = d_in[0];
  const int*  ei  = (const int*)d_in[1];
  const void* WE  = d_in[2];
  const void* bE  = d_in[3];
  const void* gam = d_in[4];
  const void* bet = d_in[5];
  const void* W1  = d_in[6];
  const void* b1  = d_in[7];
  const void* W2  = d_in[8];
  const void* b2  = d_in[9];

  float* wsf = (float*)d_ws;
  int*   wsi = (int*)d_ws;
  int*   deg   = wsi + 0;          // NN (zeroed)
  int*   fill  = wsi + 100000;     // NN (zeroed)
  float* bnsum = wsf + 200000;     // 64 (zeroed)
  float* bnsq  = wsf + 200064;     // 64 (zeroed)
  int*   flags = wsi + 200128;     // 8
  float* bnab  = wsf + 200136;     // 128
  float* dinv  = wsf + 200264;     // NN
  int*   offs  = wsi + 300264;     // NN+1
  int*   cbase = wsi + 400272;     // NCH (pad to 400384)
  unsigned short* w1hi = (unsigned short*)(wsi + 433152);  // 64*320
  unsigned short* w1lo = (unsigned short*)(wsi + 443392);
  unsigned short* w2hi = (unsigned short*)(wsi + 453632);  // 40*64
  unsigned short* w2lo = (unsigned short*)(wsi + 454912);
  int2*  ep    = (int2*)(wsi + 456192);   // 1.6M edges
  float* diag2 = wsf + 3656192;    // NN
  unsigned short* hb   = (unsigned short*)(wsi + 3756192);  // NN*64 bf16
  unsigned short* curb = (unsigned short*)(wsi + 6956192);  // NN*64 bf16
  unsigned short* zhi  = (unsigned short*)(wsi + 10156192); // NN*320 bf16
  unsigned short* zlo  = (unsigned short*)(wsi + 26156192); // NN*320 bf16
  // packed embed-W planes (64 KB each) reuse deg/fill (dead after k_fill)
  unsigned short* wph  = (unsigned short*)(wsi + 0);       // 64*512 bf16 hi
  unsigned short* wpl  = (unsigned short*)(wsi + 100000);  // 64*512 bf16 lo

  hipMemsetAsync(d_ws, 0, (size_t)200128 * 4, stream);

  k_probe     <<<1, 256, 0, stream>>>((const unsigned short*)x, ei, flags);
  k_wsplit    <<<(64 * ZD + 255) / 256, 256, 0, stream>>>(W1, flags, 64 * ZD, w1hi, w1lo);
  k_wsplit    <<<(CLS * HID + 255) / 256, 256, 0, stream>>>(W2, flags, CLS * HID, w2hi, w2lo);

  k_deg       <<<EE / 256, 256, 0, stream>>>(ei, flags, deg);
  k_chunksum  <<<NCH, 1024, 0, stream>>>(deg, cbase);
  k_scanchunks<<<1, 64, 0, stream>>>(cbase, offs + NN);
  k_offs      <<<NCH, 1024, 0, stream>>>(deg, cbase, offs, dinv);
  k_fill      <<<EE / 256, 256, 0, stream>>>(ei, flags, offs, fill, dinv, ep);

  k_wpack     <<<16, 256, 0, stream>>>(WE, flags, wph, wpl);
  k_embed     <<<NBLKE, 256, 0, stream>>>(x, wph, wpl, bE, flags, hb, bnsum, bnsq);
  k_bnfin     <<<1, 64, 0, stream>>>(bnsum, bnsq, gam, bet, flags, bnab);

  k_sp1<<<NN / 4, 256, 0, stream>>>(offs, ep, hb, bnab, diag2, zhi, zlo);
  k_sp2<<<NN / 4, 256, 0, stream>>>(offs, ep, diag2, zhi, zlo, curb);
  k_spg<<<NN / 4, 256, 0, stream>>>(offs, ep, curb, 64, diag2, nullptr, zhi, zlo, 192);
  k_spg<<<NN / 4, 256, 0, stream>>>(offs, ep, zhi + 192, ZD, diag2, curb, zhi, zlo, 256);

  k_final<<<(NN / 32 + 3) / 4, 256, 0, stream>>>(zhi, zlo, w1hi, w1lo, b1,
                                                 w2hi, w2lo, b2, flags, d_out);
}

// Round 5
// 802.042 us; speedup vs baseline: 1.1463x; 1.0339x over previous
//
#include <hip/hip_runtime.h>
#include <stdint.h>

// H2GCN forward on MI355X (gfx950). Round 11:
//  - r10 post-mortem: k_embed now <119us (out of top-5); remainder ~720us is
//    dominated by the 4 SPMM gather passes (L2/L3-resident -> invisible in
//    hbm_gbps; latency-bound).
//  - SPMM v11: paired-edge gather. Half-wave h=lane>>5 owns edge s+2i+h,
//    lane owns 2 channels (dword loads). 2x edges in flight per unrolled
//    round (16), half the instructions; cross-half shfl_xor(32) reduce.
//    Odd tails padded with w=0 on a safe index.
//  - k_embed (LDS-staged), k_final, graph build unchanged from round 10.

typedef __bf16 bf16x8 __attribute__((ext_vector_type(8)));
typedef float  f32x4  __attribute__((ext_vector_type(4)));

#define NN   100000
#define EE   800000
#define IND  512
#define HID  64
#define ZD   320
#define CLS  40
#define NCH  98           // ceil(NN/1024)
#define NBLKE 1563        // ceil(NN/64) embed blocks (4 waves x 16 rows)

static __device__ __forceinline__ float bf2f(unsigned short s) {
  unsigned int u = ((unsigned int)s) << 16;
  return __builtin_bit_cast(float, u);
}
static __device__ __forceinline__ unsigned short f2bf(float f) {
  unsigned int u = __builtin_bit_cast(unsigned int, f);
  u += 0x7FFFu + ((u >> 16) & 1u);   // RNE
  return (unsigned short)(u >> 16);
}
static __device__ __forceinline__ float ldsc(const void* p, int i, int fm) {
  return fm ? ((const float*)p)[i] : bf2f(((const unsigned short*)p)[i]);
}
static __device__ __forceinline__ float i2f(int v) { return __builtin_bit_cast(float, v); }
static __device__ __forceinline__ void split8r(f32x4 u0, f32x4 u1, bf16x8& hi, bf16x8& lo) {
  #pragma unroll
  for (int j = 0; j < 4; ++j) {
    float v0 = u0[j], v1 = u1[j];
    __bf16 h0 = (__bf16)v0, h1 = (__bf16)v1;
    hi[j] = h0;     lo[j] = (__bf16)(v0 - (float)h0);
    hi[4 + j] = h1; lo[4 + j] = (__bf16)(v1 - (float)h1);
  }
}
static __device__ __forceinline__ void splitsc(float v, unsigned short* hp, unsigned short* lp) {
  __bf16 h = (__bf16)v;
  *hp = __builtin_bit_cast(unsigned short, h);
  __bf16 l = (__bf16)(v - (float)h);
  *lp = __builtin_bit_cast(unsigned short, l);
}
// split 2 channels, pack, 4B stores to hi/lo planes
static __device__ __forceinline__ void split2(float x, float y,
                                              unsigned short* hp, unsigned short* lp) {
  __bf16 hx = (__bf16)x, hy = (__bf16)y;
  __bf16 lx = (__bf16)(x - (float)hx), ly = (__bf16)(y - (float)hy);
  unsigned int hw = (unsigned int)__builtin_bit_cast(unsigned short, hx)
                  | ((unsigned int)__builtin_bit_cast(unsigned short, hy) << 16);
  unsigned int lw = (unsigned int)__builtin_bit_cast(unsigned short, lx)
                  | ((unsigned int)__builtin_bit_cast(unsigned short, ly) << 16);
  *(unsigned int*)hp = hw;
  *(unsigned int*)lp = lw;
}
// async global->LDS, 16B per lane (dest = uniform base + lane*16)
static __device__ __forceinline__ void gload16(const void* g, void* l) {
  __builtin_amdgcn_global_load_lds(
      (const __attribute__((address_space(1))) void*)g,
      (__attribute__((address_space(3))) void*)l, 16, 0, 0);
}

// ---------------- dtype probe ----------------
__global__ void k_probe(const unsigned short* __restrict__ xs,
                        const int* __restrict__ ei, int* __restrict__ flags) {
  __shared__ int cnt_big, cnt_nz;
  if (threadIdx.x == 0) { cnt_big = 0; cnt_nz = 0; }
  __syncthreads();
  unsigned short u = xs[threadIdx.x];
  int expf = (u >> 7) & 0xFF;
  if (expf >= 0x8D) atomicAdd(&cnt_big, 1);
  if (threadIdx.x < 128 && ei[2 * threadIdx.x + 1] != 0) atomicAdd(&cnt_nz, 1);
  __syncthreads();
  if (threadIdx.x == 0) {
    flags[0] = (cnt_big >= 2) ? 1 : 0;
    flags[1] = (cnt_nz < 64) ? 1 : 0;
  }
}

// ---------------- weight pre-split (W1, W2) ----------------
__global__ void k_wsplit(const void* __restrict__ Wv, const int* __restrict__ flags,
                         int n, unsigned short* __restrict__ hi,
                         unsigned short* __restrict__ lo) {
  int i = blockIdx.x * 256 + threadIdx.x;
  if (i >= n) return;
  float v = ldsc(Wv, i, flags[0]);
  splitsc(v, hi + i, lo + i);
}

// ---------------- embed-W split + pack into MFMA fragment order -------------
__global__ void k_wpack(const void* __restrict__ Wv, const int* __restrict__ flags,
                        unsigned short* __restrict__ ph, unsigned short* __restrict__ pl) {
  int tid = blockIdx.x * 256 + threadIdx.x;
  if (tid >= 64 * 64) return;
  int f = tid >> 6, lane = tid & 63;
  int kk = f >> 2, nt = f & 3;
  int l15 = lane & 15, quad = lane >> 4;
  int fmv = flags[0];
  int src = (nt * 16 + l15) * IND + kk * 32 + quad * 8;
  size_t dst = ((size_t)f * 64 + lane) * 8;
  #pragma unroll
  for (int j = 0; j < 8; ++j) {
    float v = ldsc(Wv, src + j, fmv);
    splitsc(v, ph + dst + j, pl + dst + j);
  }
}

// ---------------- graph build ----------------
__global__ void k_deg(const int* __restrict__ ei, const int* __restrict__ flags,
                      int* __restrict__ deg) {
  int e = blockIdx.x * 256 + threadIdx.x;
  if (e >= EE) return;
  int r, c;
  if (flags[1]) { r = ((const int2*)ei)[e].x; c = ((const int2*)ei)[EE + e].x; }
  else          { r = ei[e];                  c = ei[EE + e]; }
  if (r != c) { atomicAdd(&deg[r], 1); atomicAdd(&deg[c], 1); }
}

__global__ void k_chunksum(const int* __restrict__ deg, int* __restrict__ csum) {
  __shared__ int sd[1024];
  int i = blockIdx.x * 1024 + threadIdx.x;
  sd[threadIdx.x] = (i < NN) ? deg[i] : 0;
  __syncthreads();
  for (int s = 512; s > 0; s >>= 1) {
    if (threadIdx.x < s) sd[threadIdx.x] += sd[threadIdx.x + s];
    __syncthreads();
  }
  if (threadIdx.x == 0) csum[blockIdx.x] = sd[0];
}

__global__ void k_scanchunks(int* __restrict__ csum, int* __restrict__ total) {
  if (threadIdx.x == 0) {
    int acc = 0;
    for (int i = 0; i < NCH; ++i) { int v = csum[i]; csum[i] = acc; acc += v; }
    total[0] = acc;
  }
}

__global__ void k_offs(const int* __restrict__ deg, const int* __restrict__ cbase,
                       int* __restrict__ offs, float* __restrict__ dinv) {
  __shared__ int sd[1024];
  int i = blockIdx.x * 1024 + threadIdx.x;
  int v = (i < NN) ? deg[i] : 0;
  sd[threadIdx.x] = v;
  __syncthreads();
  for (int s = 1; s < 1024; s <<= 1) {
    int t = (threadIdx.x >= s) ? sd[threadIdx.x - s] : 0;
    __syncthreads();
    sd[threadIdx.x] += t;
    __syncthreads();
  }
  if (i < NN) {
    offs[i] = cbase[blockIdx.x] + sd[threadIdx.x] - v;
    dinv[i] = (v > 0) ? rsqrtf((float)v) : 0.f;
  }
}

__global__ void k_fill(const int* __restrict__ ei, const int* __restrict__ flags,
                       const int* __restrict__ offs,
                       int* __restrict__ fill, const float* __restrict__ dinv,
                       int2* __restrict__ ep) {
  int e = blockIdx.x * 256 + threadIdx.x;
  if (e >= EE) return;
  int r, c;
  if (flags[1]) { r = ((const int2*)ei)[e].x; c = ((const int2*)ei)[EE + e].x; }
  else          { r = ei[e];                  c = ei[EE + e]; }
  if (r == c) return;
  float w = dinv[r] * dinv[c];
  int wb = __builtin_bit_cast(int, w);
  int p = offs[r] + atomicAdd(&fill[r], 1);
  ep[p] = make_int2(c, wb);
  int q = offs[c] + atomicAdd(&fill[c], 1);
  ep[q] = make_int2(r, wb);
}

// ---------------- embed GEMM: hb = bf16(relu(x @ W^T + b)), + BN stats -------
// v10 structure: block = 4 waves x 16 rows; x staged via global_load_lds,
// double-buffered; XOR swizzle both sides; W frags pinned before stage ops.
__global__ __launch_bounds__(256, 4) void k_embed(
    const void* __restrict__ xv,
    const unsigned short* __restrict__ wph, const unsigned short* __restrict__ wpl,
    const void* __restrict__ bEv, const int* __restrict__ flags,
    unsigned short* __restrict__ hb, float* __restrict__ bnsum, float* __restrict__ bnsq) {
  __shared__ char xb[2][16384] __attribute__((aligned(128)));
  __shared__ float ssum[4][64];
  __shared__ float ssq[4][64];
  const int fm = flags[0];
  const int wave = threadIdx.x >> 6, lane = threadIdx.x & 63;
  const int l15 = lane & 15, quad = lane >> 4;
  const int rb = blockIdx.x * 64;
  const int rbw = rb + wave * 16;
  f32x4 acc[4] = {};
  if (fm) {
    const char* sp[4];
    {
      const int borig = (l15 ^ (quad & 1)) * 16;
      #pragma unroll
      for (int j = 0; j < 4; ++j) {
        int grow = rb + (wave * 4 + j) * 4 + quad;
        if (grow > NN - 1) grow = NN - 1;
        sp[j] = (const char*)xv + (size_t)grow * 2048 + borig;
      }
    }
    const int p = l15 & 1;
    const int roA = (wave * 16 + l15) * 256 + quad * 32 + 16 * p;
    const int roB = (wave * 16 + l15) * 256 + quad * 32 + 16 - 16 * p;
    #pragma unroll
    for (int j = 0; j < 4; ++j)
      gload16(sp[j], &xb[0][(wave * 4 + j) * 1024]);
    __syncthreads();
    for (int c = 0; c < 8; ++c) {
      const int cur = c & 1;
      bf16x8 bh[2][4], bl[2][4];
      #pragma unroll
      for (int ks = 0; ks < 2; ++ks)
        #pragma unroll
        for (int nt = 0; nt < 4; ++nt) {
          size_t off = ((size_t)((c * 2 + ks) * 4 + nt) * 64 + lane) * 8;
          bh[ks][nt] = *(const bf16x8*)(wph + off);
          bl[ks][nt] = *(const bf16x8*)(wpl + off);
        }
      __builtin_amdgcn_sched_barrier(0);
      if (c < 7) {
        char* db = &xb[cur ^ 1][0];
        #pragma unroll
        for (int j = 0; j < 4; ++j)
          gload16(sp[j] + (c + 1) * 256, db + (wave * 4 + j) * 1024);
      }
      __builtin_amdgcn_sched_barrier(0);
      const char* cb = &xb[cur][0];
      #pragma unroll
      for (int ks = 0; ks < 2; ++ks) {
        f32x4 u0 = *(const f32x4*)(cb + roA + ks * 128);
        f32x4 u1 = *(const f32x4*)(cb + roB + ks * 128);
        bf16x8 ahi, alo;
        split8r(u0, u1, ahi, alo);
        #pragma unroll
        for (int nt = 0; nt < 4; ++nt) {
          acc[nt] = __builtin_amdgcn_mfma_f32_16x16x32_bf16(ahi, bh[ks][nt], acc[nt], 0, 0, 0);
          acc[nt] = __builtin_amdgcn_mfma_f32_16x16x32_bf16(alo, bh[ks][nt], acc[nt], 0, 0, 0);
          acc[nt] = __builtin_amdgcn_mfma_f32_16x16x32_bf16(ahi, bl[ks][nt], acc[nt], 0, 0, 0);
        }
      }
      __syncthreads();
    }
  } else {
    int row0 = rbw + l15; if (row0 > NN - 1) row0 = NN - 1;
    const unsigned short* xr0 = (const unsigned short*)xv + (size_t)row0 * IND + quad * 8;
    for (int kk = 0; kk < 16; ++kk) {
      bf16x8 bh[4];
      #pragma unroll
      for (int nt = 0; nt < 4; ++nt)
        bh[nt] = *(const bf16x8*)(wph + ((size_t)(kk * 4 + nt) * 64 + lane) * 8);
      bf16x8 a0 = *(const bf16x8*)(xr0 + kk * 32);
      #pragma unroll
      for (int nt = 0; nt < 4; ++nt)
        acc[nt] = __builtin_amdgcn_mfma_f32_16x16x32_bf16(a0, bh[nt], acc[nt], 0, 0, 0);
    }
  }
  #pragma unroll
  for (int nt = 0; nt < 4; ++nt) {
    int n = nt * 16 + l15;
    float bb = ldsc(bEv, n, fm);
    float ps = 0.f, pq = 0.f;
    #pragma unroll
    for (int r = 0; r < 4; ++r) {
      int row = rbw + quad * 4 + r;
      if (row < NN) {
        float v = fmaxf(acc[nt][r] + bb, 0.f);
        hb[(size_t)row * 64 + n] = f2bf(v);
        ps += v; pq += v * v;
      }
    }
    ps += __shfl_xor(ps, 16); pq += __shfl_xor(pq, 16);
    ps += __shfl_xor(ps, 32); pq += __shfl_xor(pq, 32);
    if (quad == 0) { ssum[wave][n] = ps; ssq[wave][n] = pq; }
  }
  __syncthreads();
  if (threadIdx.x < 64) {
    int c = threadIdx.x;
    float s = ssum[0][c] + ssum[1][c] + ssum[2][c] + ssum[3][c];
    float q = ssq[0][c] + ssq[1][c] + ssq[2][c] + ssq[3][c];
    atomicAdd(&bnsum[c], s);
    atomicAdd(&bnsq[c], q);
  }
}

__global__ void k_bnfin(const float* __restrict__ bnsum, const float* __restrict__ bnsq,
                        const void* __restrict__ gv, const void* __restrict__ bv,
                        const int* __restrict__ flags, float* __restrict__ ab) {
  int c = threadIdx.x;
  int fm = flags[0];
  if (c < 64) {
    float mu = bnsum[c] * (1.0f / (float)NN);
    float var = bnsq[c] * (1.0f / (float)NN) - mu * mu;
    float a = ldsc(gv, c, fm) / sqrtf(var + 1e-5f);
    float b = ldsc(bv, c, fm) - mu * a;
    ab[c] = a; ab[64 + c] = b;
  }
}

// ---------------- SPMM: paired-edge gather ----------------
// Half hh = lane>>5 owns edges s+2i+hh; lane owns channels {2*c2, 2*c2+1}
// (c2 = lane&31) via dword gathers. 16 edges in flight per unrolled round.
// Odd tails: pad with w=0 on safe index s. Cross-half totals via shfl_xor(32).
#define PGATHER(SRC, STRIDE)                                                    \
  float2 a2[8] = {};                                                            \
  float sw = 0.f, sq = 0.f; (void)sq;                                           \
  {                                                                             \
    const int npairs = (e - s + 1) >> 1;                                        \
    int i = 0;                                                                  \
    for (; i + 8 <= npairs; i += 8) {                                           \
      int2 q[8]; float w[8];                                                    \
      _Pragma("unroll") for (int t = 0; t < 8; ++t) {                           \
        int jj = s + 2 * (i + t) + hh;                                          \
        bool ok = jj < e;                                                       \
        q[t] = ep[ok ? jj : s];                                                 \
        w[t] = ok ? i2f(q[t].y) : 0.f;                                          \
      }                                                                         \
      unsigned int v[8];                                                        \
      _Pragma("unroll") for (int t = 0; t < 8; ++t)                             \
        v[t] = *(const unsigned int*)(SRC + (size_t)q[t].x * STRIDE + 2 * c2);  \
      _Pragma("unroll") for (int t = 0; t < 8; ++t) {                           \
        a2[t].x = fmaf(w[t], bf2f((unsigned short)(v[t] & 0xffff)), a2[t].x);   \
        a2[t].y = fmaf(w[t], bf2f((unsigned short)(v[t] >> 16)), a2[t].y);      \
        sw += w[t]; sq = fmaf(w[t], w[t], sq);                                  \
      }                                                                         \
    }                                                                           \
    for (; i < npairs; ++i) {                                                   \
      int jj = s + 2 * i + hh;                                                  \
      bool ok = jj < e;                                                         \
      int2 q = ep[ok ? jj : s];                                                 \
      float w = ok ? i2f(q.y) : 0.f;                                            \
      unsigned int v = *(const unsigned int*)(SRC + (size_t)q.x * STRIDE + 2 * c2); \
      a2[0].x = fmaf(w, bf2f((unsigned short)(v & 0xffff)), a2[0].x);           \
      a2[0].y = fmaf(w, bf2f((unsigned short)(v >> 16)), a2[0].y);              \
      sw += w; sq = fmaf(w, w, sq);                                             \
    }                                                                           \
  }                                                                             \
  float accx = ((a2[0].x + a2[1].x) + (a2[2].x + a2[3].x))                      \
             + ((a2[4].x + a2[5].x) + (a2[6].x + a2[7].x));                     \
  float accy = ((a2[0].y + a2[1].y) + (a2[2].y + a2[3].y))                      \
             + ((a2[4].y + a2[5].y) + (a2[6].y + a2[7].y));                     \
  accx += __shfl_xor(accx, 32); accy += __shfl_xor(accy, 32);                   \
  sw   += __shfl_xor(sw, 32);   sq   += __shfl_xor(sq, 32);

// SPMM1: gather hb; block0 = BN(hb[r]); block1 = h1; diag2 = Sum(w^2)
__global__ __launch_bounds__(256) void k_sp1(
    const int* __restrict__ offs, const int2* __restrict__ ep,
    const unsigned short* __restrict__ hb, const float* __restrict__ bnab,
    float* __restrict__ diag2,
    unsigned short* __restrict__ zhi, unsigned short* __restrict__ zlo) {
  const int r = blockIdx.x * 4 + (threadIdx.x >> 6);
  const int lane = threadIdx.x & 63;
  const int hh = lane >> 5, c2 = lane & 31;
  if (r >= NN) return;
  int s = offs[r], e = offs[r + 1];
  PGATHER(hb, 64)
  float2 ga = *(const float2*)(bnab + 2 * c2);
  float2 gb = *(const float2*)(bnab + 64 + 2 * c2);
  size_t zr = (size_t)r * ZD;
  unsigned int hv = *(const unsigned int*)(hb + (size_t)r * 64 + 2 * c2);
  float z0x = fmaf(ga.x, bf2f((unsigned short)(hv & 0xffff)), gb.x);
  float z0y = fmaf(ga.y, bf2f((unsigned short)(hv >> 16)), gb.y);
  float h1x = ga.x * accx + gb.x * sw;
  float h1y = ga.y * accy + gb.y * sw;
  if (hh == 0) {
    split2(z0x, z0y, zhi + zr + 2 * c2, zlo + zr + 2 * c2);
    split2(h1x, h1y, zhi + zr + 64 + 2 * c2, zlo + zr + 64 + 2 * c2);
  }
  if (lane == 0) diag2[r] = sq;
}

// SPMM2: gather block1(hi); h2 = acc - diag2*z0; block2 = h2; curb = bf16(h1+h2)
__global__ __launch_bounds__(256) void k_sp2(
    const int* __restrict__ offs, const int2* __restrict__ ep,
    const float* __restrict__ diag2,
    unsigned short* __restrict__ zhi, unsigned short* __restrict__ zlo,
    unsigned short* __restrict__ curb) {
  const int r = blockIdx.x * 4 + (threadIdx.x >> 6);
  const int lane = threadIdx.x & 63;
  const int hh = lane >> 5, c2 = lane & 31;
  if (r >= NN) return;
  int s = offs[r], e = offs[r + 1];
  const unsigned short* src = zhi + 64;
  PGATHER(src, ZD)
  size_t zr = (size_t)r * ZD;
  unsigned int zh0 = *(const unsigned int*)(zhi + zr + 2 * c2);
  unsigned int zl0 = *(const unsigned int*)(zlo + zr + 2 * c2);
  unsigned int zh1 = *(const unsigned int*)(zhi + zr + 64 + 2 * c2);
  unsigned int zl1 = *(const unsigned int*)(zlo + zr + 64 + 2 * c2);
  float z0x = bf2f((unsigned short)(zh0 & 0xffff)) + bf2f((unsigned short)(zl0 & 0xffff));
  float z0y = bf2f((unsigned short)(zh0 >> 16)) + bf2f((unsigned short)(zl0 >> 16));
  float h1x = bf2f((unsigned short)(zh1 & 0xffff)) + bf2f((unsigned short)(zl1 & 0xffff));
  float h1y = bf2f((unsigned short)(zh1 >> 16)) + bf2f((unsigned short)(zl1 >> 16));
  float d2 = diag2[r];
  float h2x = accx - d2 * z0x;
  float h2y = accy - d2 * z0y;
  if (hh == 0) {
    split2(h2x, h2y, zhi + zr + 128 + 2 * c2, zlo + zr + 128 + 2 * c2);
    unsigned int cw = (unsigned int)f2bf(h1x + h2x) | ((unsigned int)f2bf(h1y + h2y) << 16);
    *(unsigned int*)(curb + (size_t)r * 64 + 2 * c2) = cw;
  }
}

// SPMM3/4: gather src (stride ss); y = acc [- diag2*bf(corrb)]; block zoff = y
__global__ __launch_bounds__(256) void k_spg(
    const int* __restrict__ offs, const int2* __restrict__ ep,
    const unsigned short* __restrict__ src, long ss,
    const float* __restrict__ diag2, const unsigned short* __restrict__ corrb,
    unsigned short* __restrict__ zhi, unsigned short* __restrict__ zlo, long zoff) {
  const int r = blockIdx.x * 4 + (threadIdx.x >> 6);
  const int lane = threadIdx.x & 63;
  const int hh = lane >> 5, c2 = lane & 31;
  if (r >= NN) return;
  int s = offs[r], e = offs[r + 1];
  PGATHER(src, ss)
  if (corrb) {
    float d2 = diag2[r];
    unsigned int cv = *(const unsigned int*)(corrb + (size_t)r * 64 + 2 * c2);
    accx -= d2 * bf2f((unsigned short)(cv & 0xffff));
    accy -= d2 * bf2f((unsigned short)(cv >> 16));
  }
  if (hh == 0) {
    size_t zi = (size_t)r * ZD + zoff + 2 * c2;
    split2(accx, accy, zhi + zi, zlo + zi);
  }
}

// ---------------- final: out = relu(z @ W1^T + b1) @ W2^T + b2 ----------------
__global__ __launch_bounds__(256) void k_final(
    const unsigned short* __restrict__ zhi, const unsigned short* __restrict__ zlo,
    const unsigned short* __restrict__ w1hi, const unsigned short* __restrict__ w1lo,
    const void* __restrict__ b1v,
    const unsigned short* __restrict__ w2hi, const unsigned short* __restrict__ w2lo,
    const void* __restrict__ b2v,
    const int* __restrict__ flags, void* __restrict__ outv) {
  __shared__ float tls[4][2][16][68];
  const int fm = flags[0];
  const int wave = threadIdx.x >> 6, lane = threadIdx.x & 63;
  const int l15 = lane & 15, quad = lane >> 4;
  const int gid = blockIdx.x * 4 + wave;      // 0..3124 valid (32 rows each)
  const bool valid = gid < NN / 32;
  if (valid) {
    const int rb = gid * 32;
    f32x4 acc[2][4] = {};
    size_t zb[2];
    #pragma unroll
    for (int t = 0; t < 2; ++t)
      zb[t] = (size_t)(rb + t * 16 + l15) * ZD + quad * 8;
    for (int ks = 0; ks < 10; ++ks) {
      bf16x8 ahi[2], alo[2];
      #pragma unroll
      for (int t = 0; t < 2; ++t) {
        ahi[t] = *(const bf16x8*)(zhi + zb[t] + ks * 32);
        alo[t] = *(const bf16x8*)(zlo + zb[t] + ks * 32);
      }
      #pragma unroll
      for (int nt = 0; nt < 4; ++nt) {
        size_t wb = (size_t)(nt * 16 + l15) * ZD + ks * 32 + quad * 8;
        bf16x8 bhi = *(const bf16x8*)(w1hi + wb);
        bf16x8 blo = *(const bf16x8*)(w1lo + wb);
        #pragma unroll
        for (int t = 0; t < 2; ++t) {
          acc[t][nt] = __builtin_amdgcn_mfma_f32_16x16x32_bf16(ahi[t], bhi, acc[t][nt], 0, 0, 0);
          acc[t][nt] = __builtin_amdgcn_mfma_f32_16x16x32_bf16(alo[t], bhi, acc[t][nt], 0, 0, 0);
          acc[t][nt] = __builtin_amdgcn_mfma_f32_16x16x32_bf16(ahi[t], blo, acc[t][nt], 0, 0, 0);
        }
      }
    }
    #pragma unroll
    for (int nt = 0; nt < 4; ++nt) {
      int n = nt * 16 + l15;
      float bb = ldsc(b1v, n, fm);
      #pragma unroll
      for (int t = 0; t < 2; ++t)
        #pragma unroll
        for (int r = 0; r < 4; ++r)
          tls[wave][t][quad * 4 + r][n] = fmaxf(acc[t][nt][r] + bb, 0.f);
    }
  }
  __syncthreads();
  if (valid) {
    const int rb = gid * 32;
    f32x4 acc2[2][3] = {};
    #pragma unroll
    for (int ks = 0; ks < 2; ++ks) {
      bf16x8 ahi[2], alo[2];
      #pragma unroll
      for (int t = 0; t < 2; ++t)
        #pragma unroll
        for (int j = 0; j < 8; ++j) {
          float v = tls[wave][t][l15][ks * 32 + quad * 8 + j];
          __bf16 h = (__bf16)v;
          ahi[t][j] = h; alo[t][j] = (__bf16)(v - (float)h);
        }
      #pragma unroll
      for (int nt = 0; nt < 3; ++nt) {
        int n = nt * 16 + l15;
        bf16x8 bhi = {}, blo = {};
        if (n < CLS) {
          size_t wb = (size_t)n * HID + ks * 32 + quad * 8;
          bhi = *(const bf16x8*)(w2hi + wb);
          blo = *(const bf16x8*)(w2lo + wb);
        }
        #pragma unroll
        for (int t = 0; t < 2; ++t) {
          acc2[t][nt] = __builtin_amdgcn_mfma_f32_16x16x32_bf16(ahi[t], bhi, acc2[t][nt], 0, 0, 0);
          acc2[t][nt] = __builtin_amdgcn_mfma_f32_16x16x32_bf16(alo[t], bhi, acc2[t][nt], 0, 0, 0);
          acc2[t][nt] = __builtin_amdgcn_mfma_f32_16x16x32_bf16(ahi[t], blo, acc2[t][nt], 0, 0, 0);
        }
      }
    }
    #pragma unroll
    for (int nt = 0; nt < 3; ++nt) {
      int n = nt * 16 + l15;
      if (n < CLS) {
        float bb = ldsc(b2v, n, fm);
        #pragma unroll
        for (int t = 0; t < 2; ++t)
          #pragma unroll
          for (int r = 0; r < 4; ++r) {
            float v = acc2[t][nt][r] + bb;
            size_t oi = (size_t)(rb + t * 16 + quad * 4 + r) * CLS + n;
            if (fm) ((float*)outv)[oi] = v;
            else    ((unsigned short*)outv)[oi] = f2bf(v);
          }
      }
    }
  }
}

extern "C" void kernel_launch(void* const* d_in, const int* in_sizes, int n_in,
                              void* d_out, int out_size, void* d_ws, size_t ws_size,
                              hipStream_t stream) {
  (void)in_sizes; (void)n_in; (void)out_size; (void)ws_size;
  const void* x   = d_in[0];
  const int*  ei  = (const int*)d_in[1];
  const void* WE  = d_in[2];
  const void* bE  = d_in[3];
  const void* gam = d_in[4];
  const void* bet = d_in[5];
  const void* W1  = d_in[6];
  const void* b1  = d_in[7];
  const void* W2  = d_in[8];
  const void* b2  = d_in[9];

  float* wsf = (float*)d_ws;
  int*   wsi = (int*)d_ws;
  int*   deg   = wsi + 0;          // NN (zeroed)
  int*   fill  = wsi + 100000;     // NN (zeroed)
  float* bnsum = wsf + 200000;     // 64 (zeroed)
  float* bnsq  = wsf + 200064;     // 64 (zeroed)
  int*   flags = wsi + 200128;     // 8
  float* bnab  = wsf + 200136;     // 128
  float* dinv  = wsf + 200264;     // NN
  int*   offs  = wsi + 300264;     // NN+1
  int*   cbase = wsi + 400272;     // NCH (pad to 400384)
  unsigned short* w1hi = (unsigned short*)(wsi + 433152);  // 64*320
  unsigned short* w1lo = (unsigned short*)(wsi + 443392);
  unsigned short* w2hi = (unsigned short*)(wsi + 453632);  // 40*64
  unsigned short* w2lo = (unsigned short*)(wsi + 454912);
  int2*  ep    = (int2*)(wsi + 456192);   // 1.6M edges
  float* diag2 = wsf + 3656192;    // NN
  unsigned short* hb   = (unsigned short*)(wsi + 3756192);  // NN*64 bf16
  unsigned short* curb = (unsigned short*)(wsi + 6956192);  // NN*64 bf16
  unsigned short* zhi  = (unsigned short*)(wsi + 10156192); // NN*320 bf16
  unsigned short* zlo  = (unsigned short*)(wsi + 26156192); // NN*320 bf16
  // packed embed-W planes (64 KB each) reuse deg/fill (dead after k_fill)
  unsigned short* wph  = (unsigned short*)(wsi + 0);       // 64*512 bf16 hi
  unsigned short* wpl  = (unsigned short*)(wsi + 100000);  // 64*512 bf16 lo

  hipMemsetAsync(d_ws, 0, (size_t)200128 * 4, stream);

  k_probe     <<<1, 256, 0, stream>>>((const unsigned short*)x, ei, flags);
  k_wsplit    <<<(64 * ZD + 255) / 256, 256, 0, stream>>>(W1, flags, 64 * ZD, w1hi, w1lo);
  k_wsplit    <<<(CLS * HID + 255) / 256, 256, 0, stream>>>(W2, flags, CLS * HID, w2hi, w2lo);

  k_deg       <<<EE / 256, 256, 0, stream>>>(ei, flags, deg);
  k_chunksum  <<<NCH, 1024, 0, stream>>>(deg, cbase);
  k_scanchunks<<<1, 64, 0, stream>>>(cbase, offs + NN);
  k_offs      <<<NCH, 1024, 0, stream>>>(deg, cbase, offs, dinv);
  k_fill      <<<EE / 256, 256, 0, stream>>>(ei, flags, offs, fill, dinv, ep);

  k_wpack     <<<16, 256, 0, stream>>>(WE, flags, wph, wpl);
  k_embed     <<<NBLKE, 256, 0, stream>>>(x, wph, wpl, bE, flags, hb, bnsum, bnsq);
  k_bnfin     <<<1, 64, 0, stream>>>(bnsum, bnsq, gam, bet, flags, bnab);

  k_sp1<<<NN / 4, 256, 0, stream>>>(offs, ep, hb, bnab, diag2, zhi, zlo);
  k_sp2<<<NN / 4, 256, 0, stream>>>(offs, ep, diag2, zhi, zlo, curb);
  k_spg<<<NN / 4, 256, 0, stream>>>(offs, ep, curb, 64, diag2, nullptr, zhi, zlo, 192);
  k_spg<<<NN / 4, 256, 0, stream>>>(offs, ep, zhi + 192, ZD, diag2, curb, zhi, zlo, 256);

  k_final<<<(NN / 32 + 3) / 4, 256, 0, stream>>>(zhi, zlo, w1hi, w1lo, b1,
                                                 w2hi, w2lo, b2, flags, d_out);
}